// Round 5
// baseline (3359.944 us; speedup 1.0000x reference)
//
#include <hip/hip_runtime.h>

#define N_NODES 50000
#define N_EDGES 800000
#define N_ITERS 7
#define NPAD 50048
#define EDGE_TILES (N_EDGES / 64)   // 12500

typedef __attribute__((ext_vector_type(8))) short short8;
typedef __attribute__((ext_vector_type(4))) float f32x4;

#define AROW 104   // a1_lds row: 96 bf16 + 8 pad
#define XROW 296   // X row: 288 bf16 + 8 pad

static __device__ __forceinline__ unsigned short f2bf(float f) {
    unsigned int u = __float_as_uint(f);
    unsigned int r = (u + 0x7fffu + ((u >> 16) & 1u)) >> 16;
    return (unsigned short)r;
}
static __device__ __forceinline__ float bf2f(unsigned short u) {
    return __uint_as_float(((unsigned int)u) << 16);
}

// ---------------------------------------------------------------------------
// Wbig [256][288]: rows = r,z gates; cols = [W_ih[:, :64] | W_ih[:,64:]@W3 | W_hh]
__global__ __launch_bounds__(256) void k_build_wbig(const float* __restrict__ W_ih,
                                                    const float* __restrict__ W3,
                                                    const float* __restrict__ W_hh,
                                                    float* __restrict__ Wbig) {
    int idx = blockIdx.x * 256 + threadIdx.x;
    if (idx >= 256 * 288) return;
    int g = idx / 288, k = idx - g * 288;
    float v;
    if (k < 64) v = W_ih[g * 192 + k];
    else if (k < 160) {
        int kk = k - 64; float s = 0.f;
        for (int j = 0; j < 128; j++) s += W_ih[g * 192 + 64 + j] * W3[j * 96 + kk];
        v = s;
    } else v = W_hh[g * 128 + (k - 160)];
    Wbig[idx] = v;
}

// Wni [128][160]: n-gate input part (W_ih rows 256..383, with W3 fold)
__global__ __launch_bounds__(256) void k_build_wni(const float* __restrict__ W_ih,
                                                   const float* __restrict__ W3,
                                                   float* __restrict__ Wni) {
    int idx = blockIdx.x * 256 + threadIdx.x;
    if (idx >= 128 * 160) return;
    int g = idx / 160, k = idx - g * 160;
    int gg = 256 + g;
    float v;
    if (k < 64) v = W_ih[gg * 192 + k];
    else {
        int kk = k - 64; float s = 0.f;
        for (int j = 0; j < 128; j++) s += W_ih[gg * 192 + 64 + j] * W3[j * 96 + kk];
        v = s;
    }
    Wni[idx] = v;
}

__global__ __launch_bounds__(256) void k_vb3(const float* __restrict__ W_ih,
                                             const float* __restrict__ b3,
                                             float* __restrict__ vb3) {
    int g = blockIdx.x * 256 + threadIdx.x;
    if (g >= 384) return;
    float s = 0.f;
    for (int j = 0; j < 128; j++) s += W_ih[g * 192 + 64 + j] * b3[j];
    vb3[g] = s;
}

__global__ __launch_bounds__(256) void k_bsum(const float* __restrict__ b_ih,
                                              const float* __restrict__ b_hh,
                                              float* __restrict__ bsum) {
    int d = blockIdx.x * 256 + threadIdx.x;
    if (d >= 384) return;
    bsum[d] = b_ih[d] + (d < 256 ? b_hh[d] : 0.f);
}

// ---------------------------------------------------------------------------
// Pack: src fp32 (ld), element (row0+j, k) -> A-frags [Mt][KT][64][8]
__global__ __launch_bounds__(256) void k_pack2(const float* __restrict__ src,
                                               unsigned short* __restrict__ out,
                                               int Mt, int KT, int ld, int row0) {
    int idx = blockIdx.x * 256 + threadIdx.x;
    if (idx >= Mt * KT * 512) return;
    int jj = idx & 7;
    int l  = (idx >> 3) & 63;
    int tile = idx >> 9;
    int kt = tile % KT;
    int mt = tile / KT;
    int j = row0 + mt * 16 + (l & 15);
    int k = kt * 32 + (l >> 4) * 8 + jj;
    out[idx] = f2bf(src[(size_t)j * ld + k]);
}

// ---------------------------------------------------------------------------
// CSR build (once; ids fixed across iterations)
__global__ __launch_bounds__(256) void k_hist(const int* __restrict__ dst,
                                              int* __restrict__ counts) {
    int e = blockIdx.x * 256 + threadIdx.x;
    if (e < N_EDGES) atomicAdd(&counts[dst[e]], 1);
}

__global__ __launch_bounds__(1024) void k_scan(const int* __restrict__ counts,
                                               int* __restrict__ row_off) {
    __shared__ int sh[1024];
    int t = threadIdx.x;
    const int STR = 49;
    int base = t * STR;
    int s = 0;
    for (int i = 0; i < STR; i++) {
        int n = base + i;
        if (n < N_NODES) s += counts[n];
    }
    sh[t] = s;
    __syncthreads();
    for (int off = 1; off < 1024; off <<= 1) {
        int v = (t >= off) ? sh[t - off] : 0;
        __syncthreads();
        sh[t] += v;
        __syncthreads();
    }
    int run = (t == 0) ? 0 : sh[t - 1];
    for (int i = 0; i < STR; i++) {
        int n = base + i;
        if (n < N_NODES) { row_off[n] = run; run += counts[n]; }
    }
    if (t == 1023) row_off[N_NODES] = run;
}

__global__ __launch_bounds__(256) void k_permute(const int* __restrict__ src,
                                                 const int* __restrict__ dst,
                                                 const int* __restrict__ row_off,
                                                 int* __restrict__ cursor,
                                                 int* __restrict__ perm_src,
                                                 int* __restrict__ perm_dst) {
    int e = blockIdx.x * 256 + threadIdx.x;
    if (e >= N_EDGES) return;
    int d = dst[e];
    int pos = row_off[d] + atomicAdd(&cursor[d], 1);
    perm_src[pos] = src[e];
    perm_dst[pos] = d;
}

// ---------------------------------------------------------------------------
// Fused edge MLP + segmented aggregation.
// Block = 4 waves; weights cached in LDS once; loops over 64-edge tiles.
// B-frags gathered directly from hbf (no m staging). Messages -> LDS msum,
// block-level segmented sum over sorted dst, atomicAdd to r2aggT (L2).
__global__ __launch_bounds__(256) void k_edge_fused(
    const unsigned short* __restrict__ hbf,   // [N][128] bf16
    const int* __restrict__ perm_src, const int* __restrict__ perm_dst,
    const short8* __restrict__ W1Ag,          // [6*8*64] frags
    const short8* __restrict__ W2Ag,          // [6*3*64] frags
    const float* __restrict__ b1,
    const float* __restrict__ b2,
    float* __restrict__ r2aggT)               // [96][NPAD]
{
    __shared__ __attribute__((aligned(16))) short8 W1s[6 * 8 * 64];      // 49152 B
    __shared__ __attribute__((aligned(16))) short8 W2s[6 * 3 * 64];      // 18432 B
    __shared__ __attribute__((aligned(16))) unsigned short a1_lds[4][16][AROW]; // 13312 B
    __shared__ int dsts[64];
    __shared__ int segs[65];
    __shared__ int nseg_s;

    int t = threadIdx.x;
    int w = t >> 6, l = t & 63;
    int col = l & 15, krow = l >> 4;

    for (int i = t; i < 6 * 8 * 64; i += 256) W1s[i] = W1Ag[i];
    for (int i = t; i < 6 * 3 * 64; i += 256) W2s[i] = W2Ag[i];
    __syncthreads();

    unsigned short* msum = &a1_lds[0][0][0];   // overlay: 64*98 shorts = 12544 B

    for (int tile = blockIdx.x; tile < EDGE_TILES; tile += gridDim.x) {
        int e0 = tile * 64;

        // wave 0: dst list + segment boundaries (wave-local, no barrier needed)
        if (w == 0) {
            int d = perm_dst[e0 + l];
            dsts[l] = d;
            int flag = (l == 0) ? 1 : (d != perm_dst[e0 + l - 1]);
            unsigned long long mask = __ballot(flag);
            int rank = __popcll(mask & ((1ull << l) - 1));
            if (flag) segs[rank] = l;
            if (l == 0) {
                int ns = __popcll(mask);
                segs[ns] = 64;
                nseg_s = ns;
            }
        }

        int ecol = e0 + w * 16 + col;
        int sid = perm_src[ecol];
        int did = perm_dst[ecol];
        const unsigned short* srow = hbf + (size_t)sid * 128 + krow * 8;
        const unsigned short* drow = hbf + (size_t)did * 128 + krow * 8;

        // ---- L1: gather-as-B-frag ----
        f32x4 c1[6] = {};
#pragma unroll
        for (int kt = 0; kt < 4; kt++) {
            short8 b = *(const short8*)(srow + kt * 32);
#pragma unroll
            for (int mt = 0; mt < 6; mt++)
                c1[mt] = __builtin_amdgcn_mfma_f32_16x16x32_bf16(W1s[(mt * 8 + kt) * 64 + l], b, c1[mt], 0, 0, 0);
        }
#pragma unroll
        for (int kt = 0; kt < 4; kt++) {
            short8 b = *(const short8*)(drow + kt * 32);
#pragma unroll
            for (int mt = 0; mt < 6; mt++)
                c1[mt] = __builtin_amdgcn_mfma_f32_16x16x32_bf16(W1s[(mt * 8 + 4 + kt) * 64 + l], b, c1[mt], 0, 0, 0);
        }

        // ---- a1 epilogue (wave-local LDS) ----
#pragma unroll
        for (int mt = 0; mt < 6; mt++) {
#pragma unroll
            for (int r = 0; r < 4; r += 2) {
                int j0 = mt * 16 + krow * 4 + r;
                float v0 = fmaxf(c1[mt][r]     + b1[j0],     0.f);
                float v1 = fmaxf(c1[mt][r + 1] + b1[j0 + 1], 0.f);
                unsigned int p = (unsigned int)f2bf(v0) | ((unsigned int)f2bf(v1) << 16);
                *(unsigned int*)(&a1_lds[w][col][j0]) = p;
            }
        }

        // ---- L2 ----
        f32x4 c2[6] = {};
#pragma unroll
        for (int kt = 0; kt < 3; kt++) {
            short8 b = *(const short8*)(&a1_lds[w][col][kt * 32 + krow * 8]);
#pragma unroll
            for (int mt = 0; mt < 6; mt++)
                c2[mt] = __builtin_amdgcn_mfma_f32_16x16x32_bf16(W2s[(mt * 3 + kt) * 64 + l], b, c2[mt], 0, 0, 0);
        }
        __syncthreads();   // a1 free for overlay; segs/dsts published

        // ---- msg -> msum (bf16), rows = edge slot ----
        int es = w * 16 + col;
#pragma unroll
        for (int mt = 0; mt < 6; mt++) {
            int j0 = mt * 16 + krow * 4;
            unsigned int p0 = (unsigned int)f2bf(fmaxf(c2[mt][0] + b2[j0],     0.f))
                            | ((unsigned int)f2bf(fmaxf(c2[mt][1] + b2[j0 + 1], 0.f)) << 16);
            unsigned int p1 = (unsigned int)f2bf(fmaxf(c2[mt][2] + b2[j0 + 2], 0.f))
                            | ((unsigned int)f2bf(fmaxf(c2[mt][3] + b2[j0 + 3], 0.f)) << 16);
            *(unsigned int*)(&msum[es * 98 + j0])     = p0;
            *(unsigned int*)(&msum[es * 98 + j0 + 2]) = p1;
        }
        __syncthreads();

        // ---- segmented sum + atomic scatter ----
        int ns = nseg_s;
        for (int item = t; item < ns * 96; item += 256) {
            int si = item / 96;
            int k  = item - si * 96;
            int st = segs[si], en = segs[si + 1];
            int node = dsts[st];
            float s = 0.f;
            for (int e = st; e < en; e++) s += bf2f(msum[e * 98 + k]);
            atomicAdd(&r2aggT[(size_t)k * NPAD + node], s);
        }
        __syncthreads();   // protect msum/dsts/segs before next tile
    }
}

// ---------------------------------------------------------------------------
// Node phase: 1 wave per block, 16 nodes. Gates GEMMs + GRU + out-proj + hbf.
__global__ __launch_bounds__(64) void k_node_mfma(
    const float* __restrict__ inp,      // [N][64]
    const float* __restrict__ r2aggT,   // [96][NPAD]
    const int* __restrict__ row_off,    // [N+1]
    float* __restrict__ h,              // [N][128] fp32 in/out
    unsigned short* __restrict__ hbf,   // [N][128] bf16 in/out
    const short8* __restrict__ WbigA,   // 16x9
    const short8* __restrict__ WniA,    // 8x5
    const short8* __restrict__ WnhA,    // 8x4
    const short8* __restrict__ WoutA,   // 4x4
    const float* __restrict__ vb3,
    const float* __restrict__ bsum,
    const float* __restrict__ b_hh,
    const float* __restrict__ b_out,
    float* __restrict__ out, int iter)
{
    __shared__ __attribute__((aligned(16))) unsigned short X[16][XROW];
    int l = threadIdx.x;
    int nb = blockIdx.x * 16;
    int col = l & 15, krow = l >> 4;

    // ---- stage X = [inp(64) | r2(96) | h(128)] bf16 ----
    for (int idx = l; idx < 512; idx += 64) {           // inp pairs
        int i = idx >> 5, kk = (idx & 31) << 1;
        float2 v = *(const float2*)(inp + (size_t)(nb + i) * 64 + kk);
        unsigned int p = (unsigned int)f2bf(v.x) | ((unsigned int)f2bf(v.y) << 16);
        *(unsigned int*)(&X[i][kk]) = p;
    }
    for (int idx = l; idx < 1536; idx += 64) {          // r2 (k-major)
        int k = idx >> 4, i = idx & 15;
        X[i][64 + k] = f2bf(r2aggT[(size_t)k * NPAD + nb + i]);
    }
    for (int idx = l; idx < 256; idx += 64) {           // h: straight bf16 copy
        int i = idx >> 4, c = idx & 15;
        *(uint4*)(&X[i][160 + c * 8]) = ((const uint4*)(hbf + (size_t)(nb + i) * 128))[c];
    }
    __syncthreads();

    // ---- gates r,z: [256 x 288] ----
    f32x4 cg[16] = {};
#pragma unroll 3
    for (int kt = 0; kt < 9; kt++) {
        short8 b = *(const short8*)(&X[col][kt * 32 + krow * 8]);
#pragma unroll
        for (int mt = 0; mt < 16; mt++)
            cg[mt] = __builtin_amdgcn_mfma_f32_16x16x32_bf16(WbigA[(mt * 9 + kt) * 64 + l], b, cg[mt], 0, 0, 0);
    }
    // ---- i_n: [128 x 160] ----
    f32x4 ci[8] = {};
#pragma unroll
    for (int kt = 0; kt < 5; kt++) {
        short8 b = *(const short8*)(&X[col][kt * 32 + krow * 8]);
#pragma unroll
        for (int mt = 0; mt < 8; mt++)
            ci[mt] = __builtin_amdgcn_mfma_f32_16x16x32_bf16(WniA[(mt * 5 + kt) * 64 + l], b, ci[mt], 0, 0, 0);
    }
    // ---- h_n: [128 x 128] ----
    f32x4 ch[8] = {};
#pragma unroll
    for (int kt = 0; kt < 4; kt++) {
        short8 b = *(const short8*)(&X[col][160 + kt * 32 + krow * 8]);
#pragma unroll
        for (int mt = 0; mt < 8; mt++)
            ch[mt] = __builtin_amdgcn_mfma_f32_16x16x32_bf16(WnhA[(mt * 4 + kt) * 64 + l], b, ch[mt], 0, 0, 0);
    }

    int n = nb + col;
    float deg = (float)(row_off[n + 1] - row_off[n]);

    // ---- GRU epilogue ----
#pragma unroll
    for (int mt = 0; mt < 8; mt++) {
        int d0 = mt * 16 + krow * 4;
        float4 ho = *(const float4*)(h + (size_t)n * 128 + d0);
        float hv[4];
        float hov[4] = {ho.x, ho.y, ho.z, ho.w};
#pragma unroll
        for (int r = 0; r < 4; r++) {
            int d = d0 + r;
            float rp = cg[mt][r]     + bsum[d]       + deg * vb3[d];
            float zp = cg[mt + 8][r] + bsum[128 + d] + deg * vb3[128 + d];
            float ip = ci[mt][r]     + bsum[256 + d] + deg * vb3[256 + d];
            float hp = ch[mt][r]     + b_hh[256 + d];
            float rg = 1.f / (1.f + __expf(-rp));
            float zg = 1.f / (1.f + __expf(-zp));
            float ng = tanhf(ip + rg * hp);
            hv[r] = (1.f - zg) * ng + zg * hov[r];
        }
        *(float4*)(h + (size_t)n * 128 + d0) = make_float4(hv[0], hv[1], hv[2], hv[3]);
        unsigned int p0 = (unsigned int)f2bf(hv[0]) | ((unsigned int)f2bf(hv[1]) << 16);
        unsigned int p1 = (unsigned int)f2bf(hv[2]) | ((unsigned int)f2bf(hv[3]) << 16);
        *(unsigned int*)(&X[col][160 + d0])     = p0;
        *(unsigned int*)(&X[col][160 + d0 + 2]) = p1;
    }
    __syncthreads();

    // ---- out projection on h_new ----
    f32x4 co[4] = {};
#pragma unroll
    for (int kt = 0; kt < 4; kt++) {
        short8 b = *(const short8*)(&X[col][160 + kt * 32 + krow * 8]);
#pragma unroll
        for (int mt = 0; mt < 4; mt++)
            co[mt] = __builtin_amdgcn_mfma_f32_16x16x32_bf16(WoutA[(mt * 4 + kt) * 64 + l], b, co[mt], 0, 0, 0);
    }
    float* op = out + (size_t)iter * N_NODES * 64 + (size_t)n * 64;
#pragma unroll
    for (int mt = 0; mt < 4; mt++) {
        int o0 = mt * 16 + krow * 4;
        *(float4*)(op + o0) = make_float4(co[mt][0] + b_out[o0],     co[mt][1] + b_out[o0 + 1],
                                          co[mt][2] + b_out[o0 + 2], co[mt][3] + b_out[o0 + 3]);
    }

    // ---- hbf writeback ----
    for (int idx = l; idx < 256; idx += 64) {
        int i = idx >> 4, c = idx & 15;
        ((uint4*)(hbf + (size_t)(nb + i) * 128))[c] = *(const uint4*)(&X[i][160 + c * 8]);
    }
}

// ---------------------------------------------------------------------------
extern "C" void kernel_launch(void* const* d_in, const int* in_sizes, int n_in,
                              void* d_out, int out_size, void* d_ws, size_t ws_size,
                              hipStream_t stream)
{
    const float* inp   = (const float*)d_in[0];
    const int*   src   = (const int*)d_in[1];
    const int*   dst   = (const int*)d_in[2];
    const float* W1    = (const float*)d_in[3];
    const float* b1    = (const float*)d_in[4];
    const float* W2    = (const float*)d_in[5];
    const float* b2    = (const float*)d_in[6];
    const float* W3    = (const float*)d_in[7];
    const float* b3    = (const float*)d_in[8];
    const float* W_ih  = (const float*)d_in[9];
    const float* W_hh  = (const float*)d_in[10];
    const float* b_ih  = (const float*)d_in[11];
    const float* b_hh  = (const float*)d_in[12];
    const float* W_out = (const float*)d_in[13];
    const float* b_out = (const float*)d_in[14];
    float* out = (float*)d_out;

    char* ws = (char*)d_ws;
    size_t off = 0;
    auto alloc = [&](size_t bytes) -> void* {
        void* p = ws + off;
        off += (bytes + 255) & ~(size_t)255;
        return p;
    };
    float* h       = (float*)alloc((size_t)N_NODES * 128 * 4);
    unsigned short* hbf = (unsigned short*)alloc((size_t)N_NODES * 128 * 2);
    float* r2aggT  = (float*)alloc((size_t)96 * NPAD * 4);
    float* Wbig    = (float*)alloc((size_t)256 * 288 * 4);
    float* Wni     = (float*)alloc((size_t)128 * 160 * 4);
    float* vb3     = (float*)alloc((size_t)384 * 4);
    float* bsum    = (float*)alloc((size_t)384 * 4);
    unsigned short* W1A   = (unsigned short*)alloc((size_t)6 * 8 * 512 * 2);
    unsigned short* W2A   = (unsigned short*)alloc((size_t)6 * 3 * 512 * 2);
    unsigned short* WbigA = (unsigned short*)alloc((size_t)16 * 9 * 512 * 2);
    unsigned short* WniA  = (unsigned short*)alloc((size_t)8 * 5 * 512 * 2);
    unsigned short* WnhA  = (unsigned short*)alloc((size_t)8 * 4 * 512 * 2);
    unsigned short* WoutA = (unsigned short*)alloc((size_t)4 * 4 * 512 * 2);
    int*   counts  = (int*)alloc((size_t)N_NODES * 4);
    int*   cursor  = (int*)alloc((size_t)N_NODES * 4);
    int*   row_off = (int*)alloc((size_t)(N_NODES + 1) * 4);
    int*   perm_src= (int*)alloc((size_t)N_EDGES * 4);
    int*   perm_dst= (int*)alloc((size_t)N_EDGES * 4);

    // ---- one-time preprocessing ----
    hipMemsetAsync(h, 0, (size_t)N_NODES * 128 * 4, stream);
    hipMemsetAsync(hbf, 0, (size_t)N_NODES * 128 * 2, stream);
    hipMemsetAsync(counts, 0, (size_t)N_NODES * 4, stream);
    hipMemsetAsync(cursor, 0, (size_t)N_NODES * 4, stream);

    k_build_wbig<<<(256 * 288 + 255) / 256, 256, 0, stream>>>(W_ih, W3, W_hh, Wbig);
    k_build_wni<<<(128 * 160 + 255) / 256, 256, 0, stream>>>(W_ih, W3, Wni);
    k_vb3<<<2, 256, 0, stream>>>(W_ih, b3, vb3);
    k_bsum<<<2, 256, 0, stream>>>(b_ih, b_hh, bsum);

    k_pack2<<<(6 * 8 * 512 + 255) / 256, 256, 0, stream>>>(W1, W1A, 6, 8, 256, 0);
    k_pack2<<<(6 * 3 * 512 + 255) / 256, 256, 0, stream>>>(W2, W2A, 6, 3, 96, 0);
    k_pack2<<<(16 * 9 * 512 + 255) / 256, 256, 0, stream>>>(Wbig, WbigA, 16, 9, 288, 0);
    k_pack2<<<(8 * 5 * 512 + 255) / 256, 256, 0, stream>>>(Wni, WniA, 8, 5, 160, 0);
    k_pack2<<<(8 * 4 * 512 + 255) / 256, 256, 0, stream>>>(W_hh, WnhA, 8, 4, 128, 256);
    k_pack2<<<(4 * 4 * 512 + 255) / 256, 256, 0, stream>>>(W_out, WoutA, 4, 4, 128, 0);

    k_hist<<<(N_EDGES + 255) / 256, 256, 0, stream>>>(dst, counts);
    k_scan<<<1, 1024, 0, stream>>>(counts, row_off);
    k_permute<<<(N_EDGES + 255) / 256, 256, 0, stream>>>(src, dst, row_off, cursor,
                                                         perm_src, perm_dst);

    // ---- iterations ----
    for (int it = 0; it < N_ITERS; ++it) {
        hipMemsetAsync(r2aggT, 0, (size_t)96 * NPAD * 4, stream);
        k_edge_fused<<<512, 256, 0, stream>>>(hbf, perm_src, perm_dst,
                                              (const short8*)W1A, (const short8*)W2A,
                                              b1, b2, r2aggT);
        k_node_mfma<<<N_NODES / 16, 64, 0, stream>>>(inp, r2aggT, row_off, h, hbf,
                                                     (const short8*)WbigA, (const short8*)WniA,
                                                     (const short8*)WnhA, (const short8*)WoutA,
                                                     vb3, bsum, b_hh, b_out, out, it);
    }
}

// Round 6
// 2634.996 us; speedup vs baseline: 1.2751x; 1.2751x over previous
//
#include <hip/hip_runtime.h>

#define N_NODES 50000
#define N_EDGES 800000
#define N_ITERS 7
#define NPAD 50048
#define NT16 (N_EDGES / 16)   // 50000 16-edge tiles

typedef __attribute__((ext_vector_type(8))) short short8;
typedef __attribute__((ext_vector_type(4))) float f32x4;

#define AROW 104   // wave-private relay/msg row: 96 bf16 + 8 pad
#define XROW 296   // X row: 288 bf16 + 8 pad

static __device__ __forceinline__ unsigned short f2bf(float f) {
    unsigned int u = __float_as_uint(f);
    unsigned int r = (u + 0x7fffu + ((u >> 16) & 1u)) >> 16;
    return (unsigned short)r;
}
static __device__ __forceinline__ float bf2f(unsigned short u) {
    return __uint_as_float(((unsigned int)u) << 16);
}

// ---------------------------------------------------------------------------
// Wbig [256][288]: rows = r,z gates; cols = [W_ih[:, :64] | W_ih[:,64:]@W3 | W_hh]
__global__ __launch_bounds__(256) void k_build_wbig(const float* __restrict__ W_ih,
                                                    const float* __restrict__ W3,
                                                    const float* __restrict__ W_hh,
                                                    float* __restrict__ Wbig) {
    int idx = blockIdx.x * 256 + threadIdx.x;
    if (idx >= 256 * 288) return;
    int g = idx / 288, k = idx - g * 288;
    float v;
    if (k < 64) v = W_ih[g * 192 + k];
    else if (k < 160) {
        int kk = k - 64; float s = 0.f;
        for (int j = 0; j < 128; j++) s += W_ih[g * 192 + 64 + j] * W3[j * 96 + kk];
        v = s;
    } else v = W_hh[g * 128 + (k - 160)];
    Wbig[idx] = v;
}

// Wni [128][160]: n-gate input part (W_ih rows 256..383, with W3 fold)
__global__ __launch_bounds__(256) void k_build_wni(const float* __restrict__ W_ih,
                                                   const float* __restrict__ W3,
                                                   float* __restrict__ Wni) {
    int idx = blockIdx.x * 256 + threadIdx.x;
    if (idx >= 128 * 160) return;
    int g = idx / 160, k = idx - g * 160;
    int gg = 256 + g;
    float v;
    if (k < 64) v = W_ih[gg * 192 + k];
    else {
        int kk = k - 64; float s = 0.f;
        for (int j = 0; j < 128; j++) s += W_ih[gg * 192 + 64 + j] * W3[j * 96 + kk];
        v = s;
    }
    Wni[idx] = v;
}

__global__ __launch_bounds__(256) void k_vb3(const float* __restrict__ W_ih,
                                             const float* __restrict__ b3,
                                             float* __restrict__ vb3) {
    int g = blockIdx.x * 256 + threadIdx.x;
    if (g >= 384) return;
    float s = 0.f;
    for (int j = 0; j < 128; j++) s += W_ih[g * 192 + 64 + j] * b3[j];
    vb3[g] = s;
}

__global__ __launch_bounds__(256) void k_bsum(const float* __restrict__ b_ih,
                                              const float* __restrict__ b_hh,
                                              float* __restrict__ bsum) {
    int d = blockIdx.x * 256 + threadIdx.x;
    if (d >= 384) return;
    bsum[d] = b_ih[d] + (d < 256 ? b_hh[d] : 0.f);
}

// ---------------------------------------------------------------------------
// Pack: src fp32 (ld), element (row0+j, k) -> A-frags [Mt][KT][64][8]
__global__ __launch_bounds__(256) void k_pack2(const float* __restrict__ src,
                                               unsigned short* __restrict__ out,
                                               int Mt, int KT, int ld, int row0) {
    int idx = blockIdx.x * 256 + threadIdx.x;
    if (idx >= Mt * KT * 512) return;
    int jj = idx & 7;
    int l  = (idx >> 3) & 63;
    int tile = idx >> 9;
    int kt = tile % KT;
    int mt = tile / KT;
    int j = row0 + mt * 16 + (l & 15);
    int k = kt * 32 + (l >> 4) * 8 + jj;
    out[idx] = f2bf(src[(size_t)j * ld + k]);
}

// ---------------------------------------------------------------------------
// CSR build (once; ids fixed across iterations)
__global__ __launch_bounds__(256) void k_hist(const int* __restrict__ dst,
                                              int* __restrict__ counts) {
    int e = blockIdx.x * 256 + threadIdx.x;
    if (e < N_EDGES) atomicAdd(&counts[dst[e]], 1);
}

__global__ __launch_bounds__(1024) void k_scan(const int* __restrict__ counts,
                                               int* __restrict__ row_off) {
    __shared__ int sh[1024];
    int t = threadIdx.x;
    const int STR = 49;
    int base = t * STR;
    int s = 0;
    for (int i = 0; i < STR; i++) {
        int n = base + i;
        if (n < N_NODES) s += counts[n];
    }
    sh[t] = s;
    __syncthreads();
    for (int off = 1; off < 1024; off <<= 1) {
        int v = (t >= off) ? sh[t - off] : 0;
        __syncthreads();
        sh[t] += v;
        __syncthreads();
    }
    int run = (t == 0) ? 0 : sh[t - 1];
    for (int i = 0; i < STR; i++) {
        int n = base + i;
        if (n < N_NODES) { row_off[n] = run; run += counts[n]; }
    }
    if (t == 1023) row_off[N_NODES] = run;
}

__global__ __launch_bounds__(256) void k_permute(const int* __restrict__ src,
                                                 const int* __restrict__ dst,
                                                 const int* __restrict__ row_off,
                                                 int* __restrict__ cursor,
                                                 int* __restrict__ perm_src,
                                                 int* __restrict__ perm_dst) {
    int e = blockIdx.x * 256 + threadIdx.x;
    if (e >= N_EDGES) return;
    int d = dst[e];
    int pos = row_off[d] + atomicAdd(&cursor[d], 1);
    perm_src[pos] = src[e];
    perm_dst[pos] = d;
}

// ---------------------------------------------------------------------------
// Fused edge MLP + aggregation, wave-independent 16-edge tiles, no barriers
// in the main loop. Weights LDS-cached once. 2-tile software pipeline.
// Aggregate atomics go to node-major r2agg[node][96] (coalesced lines).
__global__ __launch_bounds__(256) void k_edge_fused(
    const unsigned short* __restrict__ hbf,   // [N][128] bf16
    const int* __restrict__ perm_src, const int* __restrict__ perm_dst,
    const short8* __restrict__ W1Ag,          // [6*8*64] frags
    const short8* __restrict__ W2Ag,          // [6*3*64] frags
    const float* __restrict__ b1,
    const float* __restrict__ b2,
    float* __restrict__ r2agg)                // [NPAD][96]
{
    __shared__ __attribute__((aligned(16))) short8 W1s[6 * 8 * 64];      // 49152 B
    __shared__ __attribute__((aligned(16))) short8 W2s[6 * 3 * 64];      // 18432 B
    __shared__ __attribute__((aligned(16))) unsigned short relay[4][16][AROW]; // 13312 B

    int t = threadIdx.x;
    int w = t >> 6, l = t & 63;
    int col = l & 15, krow = l >> 4;

    for (int i = t; i < 6 * 8 * 64; i += 256) W1s[i] = W1Ag[i];
    for (int i = t; i < 6 * 3 * 64; i += 256) W2s[i] = W2Ag[i];
    __syncthreads();   // only barrier in the kernel

    const int NW = 512 * 4;                    // total waves
    int wtid = blockIdx.x * 4 + w;

    auto process = [&](unsigned m16, int did, const short8* fr) {
        // ---- L1: c1 = W1 * m^T ----
        f32x4 c1[6] = {};
#pragma unroll
        for (int kt = 0; kt < 8; kt++) {
#pragma unroll
            for (int mt = 0; mt < 6; mt++)
                c1[mt] = __builtin_amdgcn_mfma_f32_16x16x32_bf16(W1s[(mt * 8 + kt) * 64 + l], fr[kt], c1[mt], 0, 0, 0);
        }
        // ---- a1 epilogue -> wave-private LDS relay ----
#pragma unroll
        for (int mt = 0; mt < 6; mt++) {
#pragma unroll
            for (int r = 0; r < 4; r += 2) {
                int j0 = mt * 16 + krow * 4 + r;
                float v0 = fmaxf(c1[mt][r]     + b1[j0],     0.f);
                float v1 = fmaxf(c1[mt][r + 1] + b1[j0 + 1], 0.f);
                unsigned int p = (unsigned int)f2bf(v0) | ((unsigned int)f2bf(v1) << 16);
                *(unsigned int*)(&relay[w][col][j0]) = p;
            }
        }
        // ---- L2 (reads relay as B-frags; wave-local, in-order DS) ----
        f32x4 c2[6] = {};
#pragma unroll
        for (int kt = 0; kt < 3; kt++) {
            short8 b = *(const short8*)(&relay[w][col][kt * 32 + krow * 8]);
#pragma unroll
            for (int mt = 0; mt < 6; mt++)
                c2[mt] = __builtin_amdgcn_mfma_f32_16x16x32_bf16(W2s[(mt * 3 + kt) * 64 + l], b, c2[mt], 0, 0, 0);
        }
        // ---- msg epilogue -> same relay region (a1 dead) ----
#pragma unroll
        for (int mt = 0; mt < 6; mt++) {
            int j0 = mt * 16 + krow * 4;
            unsigned int p0 = (unsigned int)f2bf(fmaxf(c2[mt][0] + b2[j0],     0.f))
                            | ((unsigned int)f2bf(fmaxf(c2[mt][1] + b2[j0 + 1], 0.f)) << 16);
            unsigned int p1 = (unsigned int)f2bf(fmaxf(c2[mt][2] + b2[j0 + 2], 0.f))
                            | ((unsigned int)f2bf(fmaxf(c2[mt][3] + b2[j0 + 3], 0.f)) << 16);
            *(unsigned int*)(&relay[w][col][j0])     = p0;
            *(unsigned int*)(&relay[w][col][j0 + 2]) = p1;
        }
        // ---- wave-local segmented sum + coalesced atomics ----
        int ns = __popc(m16);
        int items = ns * 96;
        for (int item = l; item < items; item += 64) {
            int si = (int)((unsigned)item / 96u);
            int k  = item - si * 96;
            unsigned m = m16;
            for (int j = 0; j < si; j++) m &= m - 1;
            int st = __ffs(m) - 1;
            unsigned mr = m & (m - 1);
            int en = mr ? (__ffs(mr) - 1) : 16;
            int node = __shfl(did, st);
            float s = 0.f;
            for (int e = st; e < en; e++) s += bf2f(relay[w][e][k]);
            atomicAdd(&r2agg[(size_t)node * 96 + k], s);
        }
    };

    for (int tile = wtid; tile < NT16; tile += 2 * NW) {
        int tB = tile + NW;
        bool hasB = (tB < NT16);

        // ---- ids + segment masks ----
        int ecolA = tile * 16 + col;
        int sidA = perm_src[ecolA];
        int didA = perm_dst[ecolA];
        int dpA = __shfl_up(didA, 1);
        unsigned mA = (unsigned)__ballot((col == 0) || (didA != dpA)) & 0xFFFFu;

        int sidB = 0, didB = 0;
        unsigned mB = 0;
        if (hasB) {
            int ecolB = tB * 16 + col;
            sidB = perm_src[ecolB];
            didB = perm_dst[ecolB];
            int dpB = __shfl_up(didB, 1);
            mB = (unsigned)__ballot((col == 0) || (didB != dpB)) & 0xFFFFu;
        }

        // ---- gather B-frags for both tiles (16 loads in flight) ----
        short8 frA[8], frB[8];
        {
            const unsigned short* sr = hbf + (size_t)sidA * 128 + krow * 8;
            const unsigned short* dr = hbf + (size_t)didA * 128 + krow * 8;
#pragma unroll
            for (int kt = 0; kt < 4; kt++) frA[kt]     = *(const short8*)(sr + kt * 32);
#pragma unroll
            for (int kt = 0; kt < 4; kt++) frA[4 + kt] = *(const short8*)(dr + kt * 32);
        }
        if (hasB) {
            const unsigned short* sr = hbf + (size_t)sidB * 128 + krow * 8;
            const unsigned short* dr = hbf + (size_t)didB * 128 + krow * 8;
#pragma unroll
            for (int kt = 0; kt < 4; kt++) frB[kt]     = *(const short8*)(sr + kt * 32);
#pragma unroll
            for (int kt = 0; kt < 4; kt++) frB[4 + kt] = *(const short8*)(dr + kt * 32);
        }

        process(mA, didA, frA);
        if (hasB) process(mB, didB, frB);
    }
}

// ---------------------------------------------------------------------------
// Node phase: 4 waves x 16 nodes. Gates GEMMs + GRU + out-proj + hbf.
__global__ __launch_bounds__(256) void k_node_mfma(
    const float* __restrict__ inp,      // [N][64]
    const float* __restrict__ r2agg,    // [NPAD][96]
    const int* __restrict__ row_off,    // [N+1]
    float* __restrict__ h,              // [N][128] fp32 in/out
    unsigned short* __restrict__ hbf,   // [N][128] bf16 in/out
    const short8* __restrict__ WbigA,   // 16x9
    const short8* __restrict__ WniA,    // 8x5
    const short8* __restrict__ WnhA,    // 8x4
    const short8* __restrict__ WoutA,   // 4x4
    const float* __restrict__ vb3,
    const float* __restrict__ bsum,
    const float* __restrict__ b_hh,
    const float* __restrict__ b_out,
    float* __restrict__ out, int iter)
{
    __shared__ __attribute__((aligned(16))) unsigned short X[4][16][XROW];
    int t = threadIdx.x;
    int w = t >> 6, l = t & 63;
    int nb = blockIdx.x * 64;
    int col = l & 15, krow = l >> 4;

    // ---- stage X = [inp(64) | r2(96) | h(128)] bf16 ----
    for (int idx = t; idx < 64 * 32; idx += 256) {      // inp pairs
        int i = idx >> 5, kk = (idx & 31) << 1;
        int n = nb + i;
        float2 v = make_float2(0.f, 0.f);
        if (n < N_NODES) v = *(const float2*)(inp + (size_t)n * 64 + kk);
        unsigned int p = (unsigned int)f2bf(v.x) | ((unsigned int)f2bf(v.y) << 16);
        *(unsigned int*)(&X[i >> 4][i & 15][kk]) = p;
    }
    for (int idx = t; idx < 64 * 96; idx += 256) {      // r2 node-major (coalesced)
        int i = (int)((unsigned)idx / 96u), k = idx - i * 96;
        X[i >> 4][i & 15][64 + k] = f2bf(r2agg[(size_t)(nb + i) * 96 + k]);
    }
    for (int idx = t; idx < 64 * 16; idx += 256) {      // h: straight bf16 copy
        int i = idx >> 4, c = idx & 15;
        int n = nb + i;
        uint4 v = make_uint4(0, 0, 0, 0);
        if (n < N_NODES) v = ((const uint4*)(hbf + (size_t)n * 128))[c];
        *(uint4*)(&X[i >> 4][i & 15][160 + c * 8]) = v;
    }
    __syncthreads();

    // ---- gates r,z: [256 x 288] ----
    f32x4 cg[16] = {};
#pragma unroll 3
    for (int kt = 0; kt < 9; kt++) {
        short8 b = *(const short8*)(&X[w][col][kt * 32 + krow * 8]);
#pragma unroll
        for (int mt = 0; mt < 16; mt++)
            cg[mt] = __builtin_amdgcn_mfma_f32_16x16x32_bf16(WbigA[(mt * 9 + kt) * 64 + l], b, cg[mt], 0, 0, 0);
    }
    // ---- i_n: [128 x 160] ----
    f32x4 ci[8] = {};
#pragma unroll
    for (int kt = 0; kt < 5; kt++) {
        short8 b = *(const short8*)(&X[w][col][kt * 32 + krow * 8]);
#pragma unroll
        for (int mt = 0; mt < 8; mt++)
            ci[mt] = __builtin_amdgcn_mfma_f32_16x16x32_bf16(WniA[(mt * 5 + kt) * 64 + l], b, ci[mt], 0, 0, 0);
    }
    // ---- h_n: [128 x 128] ----
    f32x4 ch[8] = {};
#pragma unroll
    for (int kt = 0; kt < 4; kt++) {
        short8 b = *(const short8*)(&X[w][col][160 + kt * 32 + krow * 8]);
#pragma unroll
        for (int mt = 0; mt < 8; mt++)
            ch[mt] = __builtin_amdgcn_mfma_f32_16x16x32_bf16(WnhA[(mt * 4 + kt) * 64 + l], b, ch[mt], 0, 0, 0);
    }

    int n = nb + w * 16 + col;
    bool valid = (n < N_NODES);
    float deg = 0.f;
    if (valid) deg = (float)(row_off[n + 1] - row_off[n]);

    // ---- GRU epilogue ----
#pragma unroll
    for (int mt = 0; mt < 8; mt++) {
        int d0 = mt * 16 + krow * 4;
        float4 ho = make_float4(0.f, 0.f, 0.f, 0.f);
        if (valid) ho = *(const float4*)(h + (size_t)n * 128 + d0);
        float hov[4] = {ho.x, ho.y, ho.z, ho.w};
        float hv[4];
#pragma unroll
        for (int r = 0; r < 4; r++) {
            int d = d0 + r;
            float rp = cg[mt][r]     + bsum[d]       + deg * vb3[d];
            float zp = cg[mt + 8][r] + bsum[128 + d] + deg * vb3[128 + d];
            float ip = ci[mt][r]     + bsum[256 + d] + deg * vb3[256 + d];
            float hp = ch[mt][r]     + b_hh[256 + d];
            float rg = 1.f / (1.f + __expf(-rp));
            float zg = 1.f / (1.f + __expf(-zp));
            float ng = tanhf(ip + rg * hp);
            hv[r] = (1.f - zg) * ng + zg * hov[r];
        }
        if (valid)
            *(float4*)(h + (size_t)n * 128 + d0) = make_float4(hv[0], hv[1], hv[2], hv[3]);
        unsigned int p0 = (unsigned int)f2bf(hv[0]) | ((unsigned int)f2bf(hv[1]) << 16);
        unsigned int p1 = (unsigned int)f2bf(hv[2]) | ((unsigned int)f2bf(hv[3]) << 16);
        *(unsigned int*)(&X[w][col][160 + d0])     = p0;
        *(unsigned int*)(&X[w][col][160 + d0 + 2]) = p1;
    }
    __syncthreads();

    // ---- out projection on h_new ----
    f32x4 co[4] = {};
#pragma unroll
    for (int kt = 0; kt < 4; kt++) {
        short8 b = *(const short8*)(&X[w][col][160 + kt * 32 + krow * 8]);
#pragma unroll
        for (int mt = 0; mt < 4; mt++)
            co[mt] = __builtin_amdgcn_mfma_f32_16x16x32_bf16(WoutA[(mt * 4 + kt) * 64 + l], b, co[mt], 0, 0, 0);
    }
    if (valid) {
        float* op = out + (size_t)iter * N_NODES * 64 + (size_t)n * 64;
#pragma unroll
        for (int mt = 0; mt < 4; mt++) {
            int o0 = mt * 16 + krow * 4;
            *(float4*)(op + o0) = make_float4(co[mt][0] + b_out[o0],     co[mt][1] + b_out[o0 + 1],
                                              co[mt][2] + b_out[o0 + 2], co[mt][3] + b_out[o0 + 3]);
        }
    }

    // ---- hbf writeback ----
    for (int idx = t; idx < 64 * 16; idx += 256) {
        int i = idx >> 4, c = idx & 15;
        int n2 = nb + i;
        if (n2 < N_NODES)
            ((uint4*)(hbf + (size_t)n2 * 128))[c] = *(const uint4*)(&X[i >> 4][i & 15][160 + c * 8]);
    }
}

// ---------------------------------------------------------------------------
extern "C" void kernel_launch(void* const* d_in, const int* in_sizes, int n_in,
                              void* d_out, int out_size, void* d_ws, size_t ws_size,
                              hipStream_t stream)
{
    const float* inp   = (const float*)d_in[0];
    const int*   src   = (const int*)d_in[1];
    const int*   dst   = (const int*)d_in[2];
    const float* W1    = (const float*)d_in[3];
    const float* b1    = (const float*)d_in[4];
    const float* W2    = (const float*)d_in[5];
    const float* b2    = (const float*)d_in[6];
    const float* W3    = (const float*)d_in[7];
    const float* b3    = (const float*)d_in[8];
    const float* W_ih  = (const float*)d_in[9];
    const float* W_hh  = (const float*)d_in[10];
    const float* b_ih  = (const float*)d_in[11];
    const float* b_hh  = (const float*)d_in[12];
    const float* W_out = (const float*)d_in[13];
    const float* b_out = (const float*)d_in[14];
    float* out = (float*)d_out;

    char* ws = (char*)d_ws;
    size_t off = 0;
    auto alloc = [&](size_t bytes) -> void* {
        void* p = ws + off;
        off += (bytes + 255) & ~(size_t)255;
        return p;
    };
    float* h       = (float*)alloc((size_t)N_NODES * 128 * 4);
    unsigned short* hbf = (unsigned short*)alloc((size_t)N_NODES * 128 * 2);
    float* r2agg   = (float*)alloc((size_t)NPAD * 96 * 4);
    float* Wbig    = (float*)alloc((size_t)256 * 288 * 4);
    float* Wni     = (float*)alloc((size_t)128 * 160 * 4);
    float* vb3     = (float*)alloc((size_t)384 * 4);
    float* bsum    = (float*)alloc((size_t)384 * 4);
    unsigned short* W1A   = (unsigned short*)alloc((size_t)6 * 8 * 512 * 2);
    unsigned short* W2A   = (unsigned short*)alloc((size_t)6 * 3 * 512 * 2);
    unsigned short* WbigA = (unsigned short*)alloc((size_t)16 * 9 * 512 * 2);
    unsigned short* WniA  = (unsigned short*)alloc((size_t)8 * 5 * 512 * 2);
    unsigned short* WnhA  = (unsigned short*)alloc((size_t)8 * 4 * 512 * 2);
    unsigned short* WoutA = (unsigned short*)alloc((size_t)4 * 4 * 512 * 2);
    int*   counts  = (int*)alloc((size_t)N_NODES * 4);
    int*   cursor  = (int*)alloc((size_t)N_NODES * 4);
    int*   row_off = (int*)alloc((size_t)(N_NODES + 1) * 4);
    int*   perm_src= (int*)alloc((size_t)N_EDGES * 4);
    int*   perm_dst= (int*)alloc((size_t)N_EDGES * 4);

    // ---- one-time preprocessing ----
    hipMemsetAsync(h, 0, (size_t)N_NODES * 128 * 4, stream);
    hipMemsetAsync(hbf, 0, (size_t)N_NODES * 128 * 2, stream);
    hipMemsetAsync(counts, 0, (size_t)N_NODES * 4, stream);
    hipMemsetAsync(cursor, 0, (size_t)N_NODES * 4, stream);

    k_build_wbig<<<(256 * 288 + 255) / 256, 256, 0, stream>>>(W_ih, W3, W_hh, Wbig);
    k_build_wni<<<(128 * 160 + 255) / 256, 256, 0, stream>>>(W_ih, W3, Wni);
    k_vb3<<<2, 256, 0, stream>>>(W_ih, b3, vb3);
    k_bsum<<<2, 256, 0, stream>>>(b_ih, b_hh, bsum);

    k_pack2<<<(6 * 8 * 512 + 255) / 256, 256, 0, stream>>>(W1, W1A, 6, 8, 256, 0);
    k_pack2<<<(6 * 3 * 512 + 255) / 256, 256, 0, stream>>>(W2, W2A, 6, 3, 96, 0);
    k_pack2<<<(16 * 9 * 512 + 255) / 256, 256, 0, stream>>>(Wbig, WbigA, 16, 9, 288, 0);
    k_pack2<<<(8 * 5 * 512 + 255) / 256, 256, 0, stream>>>(Wni, WniA, 8, 5, 160, 0);
    k_pack2<<<(8 * 4 * 512 + 255) / 256, 256, 0, stream>>>(W_hh, WnhA, 8, 4, 128, 256);
    k_pack2<<<(4 * 4 * 512 + 255) / 256, 256, 0, stream>>>(W_out, WoutA, 4, 4, 128, 0);

    k_hist<<<(N_EDGES + 255) / 256, 256, 0, stream>>>(dst, counts);
    k_scan<<<1, 1024, 0, stream>>>(counts, row_off);
    k_permute<<<(N_EDGES + 255) / 256, 256, 0, stream>>>(src, dst, row_off, cursor,
                                                         perm_src, perm_dst);

    // ---- iterations ----
    for (int it = 0; it < N_ITERS; ++it) {
        hipMemsetAsync(r2agg, 0, (size_t)NPAD * 96 * 4, stream);
        k_edge_fused<<<512, 256, 0, stream>>>(hbf, perm_src, perm_dst,
                                              (const short8*)W1A, (const short8*)W2A,
                                              b1, b2, r2agg);
        k_node_mfma<<<(N_NODES + 63) / 64, 256, 0, stream>>>(inp, r2agg, row_off, h, hbf,
                                                     (const short8*)WbigA, (const short8*)WniA,
                                                     (const short8*)WnhA, (const short8*)WoutA,
                                                     vb3, bsum, b_hh, b_out, out, it);
    }
}

// Round 8
// 2237.562 us; speedup vs baseline: 1.5016x; 1.1776x over previous
//
#include <hip/hip_runtime.h>

#define N_NODES 50000
#define N_EDGES 800000
#define N_ITERS 7
#define NPAD 50048
#define NT16 (N_EDGES / 16)   // 50000 16-edge tiles

typedef __attribute__((ext_vector_type(8))) short short8;
typedef __attribute__((ext_vector_type(4))) float f32x4;

#define AROW 104   // wave-private relay row: 96 bf16 + 8 pad
#define XROW 296   // X row: 288 bf16 + 8 pad

static __device__ __forceinline__ unsigned short f2bf(float f) {
    unsigned int u = __float_as_uint(f);
    unsigned int r = (u + 0x7fffu + ((u >> 16) & 1u)) >> 16;
    return (unsigned short)r;
}
static __device__ __forceinline__ float bf2f(unsigned short u) {
    return __uint_as_float(((unsigned int)u) << 16);
}
static __device__ __forceinline__ float fast_tanh(float x) {
    float xc = fminf(fmaxf(x, -15.f), 15.f);
    float t = __expf(2.f * xc);
    return (t - 1.f) / (t + 1.f);
}

// one segmented-scan step over the 16-lane row group (row_shr:OFF, bound_ctrl=1)
template <int CTRL>
static __device__ __forceinline__ void seg_step(float (&s)[24], unsigned& fl) {
    unsigned fv = (unsigned)__builtin_amdgcn_update_dpp(0, (int)fl, CTRL, 0xf, 0xf, true);
    float g = fl ? 0.f : 1.f;
#pragma unroll
    for (int q = 0; q < 24; q++) {
        int sv = __builtin_amdgcn_update_dpp(0, __float_as_int(s[q]), CTRL, 0xf, 0xf, true);
        s[q] += __int_as_float(sv) * g;
    }
    fl |= fv;
}

// ---------------------------------------------------------------------------
// Wbig [256][288]: rows = r,z gates; cols = [W_ih[:, :64] | W_ih[:,64:]@W3 | W_hh]
__global__ __launch_bounds__(256) void k_build_wbig(const float* __restrict__ W_ih,
                                                    const float* __restrict__ W3,
                                                    const float* __restrict__ W_hh,
                                                    float* __restrict__ Wbig) {
    int idx = blockIdx.x * 256 + threadIdx.x;
    if (idx >= 256 * 288) return;
    int g = idx / 288, k = idx - g * 288;
    float v;
    if (k < 64) v = W_ih[g * 192 + k];
    else if (k < 160) {
        int kk = k - 64; float s = 0.f;
        for (int j = 0; j < 128; j++) s += W_ih[g * 192 + 64 + j] * W3[j * 96 + kk];
        v = s;
    } else v = W_hh[g * 128 + (k - 160)];
    Wbig[idx] = v;
}

// Wni [128][160]: n-gate input part (W_ih rows 256..383, with W3 fold)
__global__ __launch_bounds__(256) void k_build_wni(const float* __restrict__ W_ih,
                                                   const float* __restrict__ W3,
                                                   float* __restrict__ Wni) {
    int idx = blockIdx.x * 256 + threadIdx.x;
    if (idx >= 128 * 160) return;
    int g = idx / 160, k = idx - g * 160;
    int gg = 256 + g;
    float v;
    if (k < 64) v = W_ih[gg * 192 + k];
    else {
        int kk = k - 64; float s = 0.f;
        for (int j = 0; j < 128; j++) s += W_ih[gg * 192 + 64 + j] * W3[j * 96 + kk];
        v = s;
    }
    Wni[idx] = v;
}

__global__ __launch_bounds__(256) void k_vb3(const float* __restrict__ W_ih,
                                             const float* __restrict__ b3,
                                             float* __restrict__ vb3) {
    int g = blockIdx.x * 256 + threadIdx.x;
    if (g >= 384) return;
    float s = 0.f;
    for (int j = 0; j < 128; j++) s += W_ih[g * 192 + 64 + j] * b3[j];
    vb3[g] = s;
}

__global__ __launch_bounds__(256) void k_bsum(const float* __restrict__ b_ih,
                                              const float* __restrict__ b_hh,
                                              float* __restrict__ bsum) {
    int d = blockIdx.x * 256 + threadIdx.x;
    if (d >= 384) return;
    bsum[d] = b_ih[d] + (d < 256 ? b_hh[d] : 0.f);
}

// ---------------------------------------------------------------------------
// Pack: src fp32 (ld), element (row0+j, k) -> A-frags [Mt][KT][64][8]
__global__ __launch_bounds__(256) void k_pack2(const float* __restrict__ src,
                                               unsigned short* __restrict__ out,
                                               int Mt, int KT, int ld, int row0) {
    int idx = blockIdx.x * 256 + threadIdx.x;
    if (idx >= Mt * KT * 512) return;
    int jj = idx & 7;
    int l  = (idx >> 3) & 63;
    int tile = idx >> 9;
    int kt = tile % KT;
    int mt = tile / KT;
    int j = row0 + mt * 16 + (l & 15);
    int k = kt * 32 + (l >> 4) * 8 + jj;
    out[idx] = f2bf(src[(size_t)j * ld + k]);
}

// ---------------------------------------------------------------------------
// CSR build (once; ids fixed across iterations)
__global__ __launch_bounds__(256) void k_hist(const int* __restrict__ dst,
                                              int* __restrict__ counts) {
    int e = blockIdx.x * 256 + threadIdx.x;
    if (e < N_EDGES) atomicAdd(&counts[dst[e]], 1);
}

__global__ __launch_bounds__(1024) void k_scan(const int* __restrict__ counts,
                                               int* __restrict__ row_off) {
    __shared__ int sh[1024];
    int t = threadIdx.x;
    const int STR = 49;
    int base = t * STR;
    int s = 0;
    for (int i = 0; i < STR; i++) {
        int n = base + i;
        if (n < N_NODES) s += counts[n];
    }
    sh[t] = s;
    __syncthreads();
    for (int off = 1; off < 1024; off <<= 1) {
        int v = (t >= off) ? sh[t - off] : 0;
        __syncthreads();
        sh[t] += v;
        __syncthreads();
    }
    int run = (t == 0) ? 0 : sh[t - 1];
    for (int i = 0; i < STR; i++) {
        int n = base + i;
        if (n < N_NODES) { row_off[n] = run; run += counts[n]; }
    }
    if (t == 1023) row_off[N_NODES] = run;
}

__global__ __launch_bounds__(256) void k_permute(const int* __restrict__ src,
                                                 const int* __restrict__ dst,
                                                 const int* __restrict__ row_off,
                                                 int* __restrict__ cursor,
                                                 int* __restrict__ perm_src,
                                                 int* __restrict__ perm_dst) {
    int e = blockIdx.x * 256 + threadIdx.x;
    if (e >= N_EDGES) return;
    int d = dst[e];
    int pos = row_off[d] + atomicAdd(&cursor[d], 1);
    perm_src[pos] = src[e];
    perm_dst[pos] = d;
}

// ---------------------------------------------------------------------------
// Fused edge MLP + aggregation. Wave-independent 16-edge tiles, no barriers in
// the main loop. Weights LDS-cached. Software-pipelined tile rotation.
// Aggregation: DPP segmented scan across the 16-col lane group (fp32, in-reg),
// segment-end lanes issue atomics to node-major r2agg.
__global__ __launch_bounds__(256) void k_edge_fused(
    const unsigned short* __restrict__ hbf,   // [N][128] bf16
    const int* __restrict__ perm_src, const int* __restrict__ perm_dst,
    const short8* __restrict__ W1Ag,          // [6*8*64] frags
    const short8* __restrict__ W2Ag,          // [6*3*64] frags
    const float* __restrict__ b1,
    const float* __restrict__ b2,
    float* __restrict__ r2agg)                // [NPAD][96]
{
    __shared__ __attribute__((aligned(16))) short8 W1s[6 * 8 * 64];      // 49152 B
    __shared__ __attribute__((aligned(16))) short8 W2s[6 * 3 * 64];      // 18432 B
    __shared__ __attribute__((aligned(16))) unsigned short relay[4][16][AROW]; // 13312 B

    int t = threadIdx.x;
    int w = t >> 6, l = t & 63;
    int col = l & 15, krow = l >> 4;

    for (int i = t; i < 6 * 8 * 64; i += 256) W1s[i] = W1Ag[i];
    for (int i = t; i < 6 * 3 * 64; i += 256) W2s[i] = W2Ag[i];
    __syncthreads();   // only barrier in the kernel

    const int NW = 512 * 4;
    int wtid = blockIdx.x * 4 + w;

    auto loadtile = [&](int tile, unsigned& m16, int& did, short8* fr) {
        int ecol = tile * 16 + col;
        int sid = perm_src[ecol];
        did = perm_dst[ecol];
        int dp = __shfl_up(did, 1);
        m16 = (unsigned)__ballot((col == 0) || (did != dp)) & 0xFFFFu;
        const unsigned short* sr = hbf + (size_t)sid * 128 + krow * 8;
        const unsigned short* dr = hbf + (size_t)did * 128 + krow * 8;
#pragma unroll
        for (int kt = 0; kt < 4; kt++) fr[kt]     = *(const short8*)(sr + kt * 32);
#pragma unroll
        for (int kt = 0; kt < 4; kt++) fr[4 + kt] = *(const short8*)(dr + kt * 32);
    };

    auto process = [&](unsigned m16, int did, const short8* fr) {
        // ---- L1: c1 = W1 * m^T ----
        f32x4 c1[6] = {};
#pragma unroll
        for (int kt = 0; kt < 8; kt++) {
#pragma unroll
            for (int mt = 0; mt < 6; mt++)
                c1[mt] = __builtin_amdgcn_mfma_f32_16x16x32_bf16(W1s[(mt * 8 + kt) * 64 + l], fr[kt], c1[mt], 0, 0, 0);
        }
        // ---- a1 epilogue -> wave-private LDS relay (layout swap for L2 B-frags) ----
#pragma unroll
        for (int mt = 0; mt < 6; mt++) {
#pragma unroll
            for (int r = 0; r < 4; r += 2) {
                int j0 = mt * 16 + krow * 4 + r;
                float v0 = fmaxf(c1[mt][r]     + b1[j0],     0.f);
                float v1 = fmaxf(c1[mt][r + 1] + b1[j0 + 1], 0.f);
                unsigned int p = (unsigned int)f2bf(v0) | ((unsigned int)f2bf(v1) << 16);
                *(unsigned int*)(&relay[w][col][j0]) = p;
            }
        }
        // ---- L2 ----
        f32x4 c2[6] = {};
#pragma unroll
        for (int kt = 0; kt < 3; kt++) {
            short8 b = *(const short8*)(&relay[w][col][kt * 32 + krow * 8]);
#pragma unroll
            for (int mt = 0; mt < 6; mt++)
                c2[mt] = __builtin_amdgcn_mfma_f32_16x16x32_bf16(W2s[(mt * 3 + kt) * 64 + l], b, c2[mt], 0, 0, 0);
        }
        // ---- msg (bias+relu) stays in registers ----
        float s[24];
#pragma unroll
        for (int mt = 0; mt < 6; mt++)
#pragma unroll
            for (int r = 0; r < 4; r++) {
                int j = mt * 16 + krow * 4 + r;
                s[mt * 4 + r] = fmaxf(c2[mt][r] + b2[j], 0.f);
            }
        // ---- segmented inclusive scan over col (DPP row_shr within 16 lanes) ----
        unsigned fl = (m16 >> col) & 1u;
        seg_step<0x111>(s, fl);   // row_shr:1
        seg_step<0x112>(s, fl);   // row_shr:2
        seg_step<0x114>(s, fl);   // row_shr:4
        seg_step<0x118>(s, fl);   // row_shr:8
        // ---- segment-end lanes scatter (4 krow lanes cover all 96 dims) ----
        bool is_end = (col == 15) || ((m16 >> (col + 1)) & 1u);
        if (is_end) {
            float* base = r2agg + (size_t)did * 96 + krow * 4;
#pragma unroll
            for (int mt = 0; mt < 6; mt++)
#pragma unroll
                for (int r = 0; r < 4; r++)
                    atomicAdd(base + mt * 16 + r, s[mt * 4 + r]);
        }
    };

    // ---- software-pipelined tile loop: next tile's loads fly under process ----
    int t0 = wtid;
    if (t0 < NT16) {
        unsigned mA, mB; int didA, didB;
        short8 frA[8], frB[8];
        loadtile(t0, mA, didA, frA);
        for (;;) {
            int t1 = t0 + NW;
            bool hasB = (t1 < NT16);
            if (hasB) loadtile(t1, mB, didB, frB);
            process(mA, didA, frA);
            if (!hasB) break;
            int t2 = t1 + NW;
            bool hasA = (t2 < NT16);
            if (hasA) loadtile(t2, mA, didA, frA);
            process(mB, didB, frB);
            if (!hasA) break;
            t0 = t2;
        }
    }
}

// ---------------------------------------------------------------------------
// Node phase: 4 waves x 16 nodes. Gates GEMMs + GRU + out-proj + hbf.
__global__ __launch_bounds__(256) void k_node_mfma(
    const float* __restrict__ inp,      // [N][64]
    const float* __restrict__ r2agg,    // [NPAD][96]
    const int* __restrict__ row_off,    // [N+1]
    float* __restrict__ h,              // [N][128] fp32 in/out
    unsigned short* __restrict__ hbf,   // [N][128] bf16 in/out
    const short8* __restrict__ WbigA,   // 16x9
    const short8* __restrict__ WniA,    // 8x5
    const short8* __restrict__ WnhA,    // 8x4
    const short8* __restrict__ WoutA,   // 4x4
    const float* __restrict__ vb3,
    const float* __restrict__ bsum,
    const float* __restrict__ b_hh,
    const float* __restrict__ b_out,
    float* __restrict__ out, int iter)
{
    __shared__ __attribute__((aligned(16))) unsigned short X[4][16][XROW];
    int t = threadIdx.x;
    int w = t >> 6, l = t & 63;
    int nb = blockIdx.x * 64;
    int col = l & 15, krow = l >> 4;

    // ---- stage X = [inp(64) | r2(96) | h(128)] bf16 ----
    for (int idx = t; idx < 64 * 32; idx += 256) {      // inp pairs
        int i = idx >> 5, kk = (idx & 31) << 1;
        int n = nb + i;
        float2 v = make_float2(0.f, 0.f);
        if (n < N_NODES) v = *(const float2*)(inp + (size_t)n * 64 + kk);
        unsigned int p = (unsigned int)f2bf(v.x) | ((unsigned int)f2bf(v.y) << 16);
        *(unsigned int*)(&X[i >> 4][i & 15][kk]) = p;
    }
    for (int idx = t; idx < 64 * 96; idx += 256) {      // r2 node-major (coalesced)
        int i = (int)((unsigned)idx / 96u), k = idx - i * 96;
        X[i >> 4][i & 15][64 + k] = f2bf(r2agg[(size_t)(nb + i) * 96 + k]);
    }
    for (int idx = t; idx < 64 * 16; idx += 256) {      // h: straight bf16 copy
        int i = idx >> 4, c = idx & 15;
        int n = nb + i;
        uint4 v = make_uint4(0, 0, 0, 0);
        if (n < N_NODES) v = ((const uint4*)(hbf + (size_t)n * 128))[c];
        *(uint4*)(&X[i >> 4][i & 15][160 + c * 8]) = v;
    }
    __syncthreads();

    // ---- gates r,z: [256 x 288] ----
    f32x4 cg[16] = {};
#pragma unroll 3
    for (int kt = 0; kt < 9; kt++) {
        short8 b = *(const short8*)(&X[w][col][kt * 32 + krow * 8]);
#pragma unroll
        for (int mt = 0; mt < 16; mt++)
            cg[mt] = __builtin_amdgcn_mfma_f32_16x16x32_bf16(WbigA[(mt * 9 + kt) * 64 + l], b, cg[mt], 0, 0, 0);
    }
    // ---- i_n: [128 x 160] ----
    f32x4 ci[8] = {};
#pragma unroll
    for (int kt = 0; kt < 5; kt++) {
        short8 b = *(const short8*)(&X[w][col][kt * 32 + krow * 8]);
#pragma unroll
        for (int mt = 0; mt < 8; mt++)
            ci[mt] = __builtin_amdgcn_mfma_f32_16x16x32_bf16(WniA[(mt * 5 + kt) * 64 + l], b, ci[mt], 0, 0, 0);
    }
    // ---- h_n: [128 x 128] ----
    f32x4 ch[8] = {};
#pragma unroll
    for (int kt = 0; kt < 4; kt++) {
        short8 b = *(const short8*)(&X[w][col][160 + kt * 32 + krow * 8]);
#pragma unroll
        for (int mt = 0; mt < 8; mt++)
            ch[mt] = __builtin_amdgcn_mfma_f32_16x16x32_bf16(WnhA[(mt * 4 + kt) * 64 + l], b, ch[mt], 0, 0, 0);
    }

    int n = nb + w * 16 + col;
    bool valid = (n < N_NODES);
    float deg = 0.f;
    if (valid) deg = (float)(row_off[n + 1] - row_off[n]);

    // ---- GRU epilogue ----
#pragma unroll
    for (int mt = 0; mt < 8; mt++) {
        int d0 = mt * 16 + krow * 4;
        float4 ho = make_float4(0.f, 0.f, 0.f, 0.f);
        if (valid) ho = *(const float4*)(h + (size_t)n * 128 + d0);
        float hov[4] = {ho.x, ho.y, ho.z, ho.w};
        float hv[4];
#pragma unroll
        for (int r = 0; r < 4; r++) {
            int d = d0 + r;
            float rp = cg[mt][r]     + bsum[d]       + deg * vb3[d];
            float zp = cg[mt + 8][r] + bsum[128 + d] + deg * vb3[128 + d];
            float ip = ci[mt][r]     + bsum[256 + d] + deg * vb3[256 + d];
            float hp = ch[mt][r]     + b_hh[256 + d];
            float rg = 1.f / (1.f + __expf(-rp));
            float zg = 1.f / (1.f + __expf(-zp));
            float ng = fast_tanh(ip + rg * hp);
            hv[r] = (1.f - zg) * ng + zg * hov[r];
        }
        if (valid)
            *(float4*)(h + (size_t)n * 128 + d0) = make_float4(hv[0], hv[1], hv[2], hv[3]);
        unsigned int p0 = (unsigned int)f2bf(hv[0]) | ((unsigned int)f2bf(hv[1]) << 16);
        unsigned int p1 = (unsigned int)f2bf(hv[2]) | ((unsigned int)f2bf(hv[3]) << 16);
        *(unsigned int*)(&X[w][col][160 + d0])     = p0;
        *(unsigned int*)(&X[w][col][160 + d0 + 2]) = p1;
    }
    __syncthreads();

    // ---- out projection on h_new ----
    f32x4 co[4] = {};
#pragma unroll
    for (int kt = 0; kt < 4; kt++) {
        short8 b = *(const short8*)(&X[w][col][160 + kt * 32 + krow * 8]);
#pragma unroll
        for (int mt = 0; mt < 4; mt++)
            co[mt] = __builtin_amdgcn_mfma_f32_16x16x32_bf16(WoutA[(mt * 4 + kt) * 64 + l], b, co[mt], 0, 0, 0);
    }
    if (valid) {
        float* op = out + (size_t)iter * N_NODES * 64 + (size_t)n * 64;
#pragma unroll
        for (int mt = 0; mt < 4; mt++) {
            int o0 = mt * 16 + krow * 4;
            *(float4*)(op + o0) = make_float4(co[mt][0] + b_out[o0],     co[mt][1] + b_out[o0 + 1],
                                              co[mt][2] + b_out[o0 + 2], co[mt][3] + b_out[o0 + 3]);
        }
    }

    // ---- hbf writeback ----
    for (int idx = t; idx < 64 * 16; idx += 256) {
        int i = idx >> 4, c = idx & 15;
        int n2 = nb + i;
        if (n2 < N_NODES)
            ((uint4*)(hbf + (size_t)n2 * 128))[c] = *(const uint4*)(&X[i >> 4][i & 15][160 + c * 8]);
    }
}

// ---------------------------------------------------------------------------
extern "C" void kernel_launch(void* const* d_in, const int* in_sizes, int n_in,
                              void* d_out, int out_size, void* d_ws, size_t ws_size,
                              hipStream_t stream)
{
    const float* inp   = (const float*)d_in[0];
    const int*   src   = (const int*)d_in[1];
    const int*   dst   = (const int*)d_in[2];
    const float* W1    = (const float*)d_in[3];
    const float* b1    = (const float*)d_in[4];
    const float* W2    = (const float*)d_in[5];
    const float* b2    = (const float*)d_in[6];
    const float* W3    = (const float*)d_in[7];
    const float* b3    = (const float*)d_in[8];
    const float* W_ih  = (const float*)d_in[9];
    const float* W_hh  = (const float*)d_in[10];
    const float* b_ih  = (const float*)d_in[11];
    const float* b_hh  = (const float*)d_in[12];
    const float* W_out = (const float*)d_in[13];
    const float* b_out = (const float*)d_in[14];
    float* out = (float*)d_out;

    char* ws = (char*)d_ws;
    size_t off = 0;
    auto alloc = [&](size_t bytes) -> void* {
        void* p = ws + off;
        off += (bytes + 255) & ~(size_t)255;
        return p;
    };
    float* h       = (float*)alloc((size_t)N_NODES * 128 * 4);
    unsigned short* hbf = (unsigned short*)alloc((size_t)N_NODES * 128 * 2);
    float* r2agg   = (float*)alloc((size_t)NPAD * 96 * 4);
    float* Wbig    = (float*)alloc((size_t)256 * 288 * 4);
    float* Wni     = (float*)alloc((size_t)128 * 160 * 4);
    float* vb3     = (float*)alloc((size_t)384 * 4);
    float* bsum    = (float*)alloc((size_t)384 * 4);
    unsigned short* W1A   = (unsigned short*)alloc((size_t)6 * 8 * 512 * 2);
    unsigned short* W2A   = (unsigned short*)alloc((size_t)6 * 3 * 512 * 2);
    unsigned short* WbigA = (unsigned short*)alloc((size_t)16 * 9 * 512 * 2);
    unsigned short* WniA  = (unsigned short*)alloc((size_t)8 * 5 * 512 * 2);
    unsigned short* WnhA  = (unsigned short*)alloc((size_t)8 * 4 * 512 * 2);
    unsigned short* WoutA = (unsigned short*)alloc((size_t)4 * 4 * 512 * 2);
    int*   counts  = (int*)alloc((size_t)N_NODES * 4);
    int*   cursor  = (int*)alloc((size_t)N_NODES * 4);
    int*   row_off = (int*)alloc((size_t)(N_NODES + 1) * 4);
    int*   perm_src= (int*)alloc((size_t)N_EDGES * 4);
    int*   perm_dst= (int*)alloc((size_t)N_EDGES * 4);

    // ---- one-time preprocessing ----
    hipMemsetAsync(h, 0, (size_t)N_NODES * 128 * 4, stream);
    hipMemsetAsync(hbf, 0, (size_t)N_NODES * 128 * 2, stream);
    hipMemsetAsync(counts, 0, (size_t)N_NODES * 4, stream);
    hipMemsetAsync(cursor, 0, (size_t)N_NODES * 4, stream);

    k_build_wbig<<<(256 * 288 + 255) / 256, 256, 0, stream>>>(W_ih, W3, W_hh, Wbig);
    k_build_wni<<<(128 * 160 + 255) / 256, 256, 0, stream>>>(W_ih, W3, Wni);
    k_vb3<<<2, 256, 0, stream>>>(W_ih, b3, vb3);
    k_bsum<<<2, 256, 0, stream>>>(b_ih, b_hh, bsum);

    k_pack2<<<(6 * 8 * 512 + 255) / 256, 256, 0, stream>>>(W1, W1A, 6, 8, 256, 0);
    k_pack2<<<(6 * 3 * 512 + 255) / 256, 256, 0, stream>>>(W2, W2A, 6, 3, 96, 0);
    k_pack2<<<(16 * 9 * 512 + 255) / 256, 256, 0, stream>>>(Wbig, WbigA, 16, 9, 288, 0);
    k_pack2<<<(8 * 5 * 512 + 255) / 256, 256, 0, stream>>>(Wni, WniA, 8, 5, 160, 0);
    k_pack2<<<(8 * 4 * 512 + 255) / 256, 256, 0, stream>>>(W_hh, WnhA, 8, 4, 128, 256);
    k_pack2<<<(4 * 4 * 512 + 255) / 256, 256, 0, stream>>>(W_out, WoutA, 4, 4, 128, 0);

    k_hist<<<(N_EDGES + 255) / 256, 256, 0, stream>>>(dst, counts);
    k_scan<<<1, 1024, 0, stream>>>(counts, row_off);
    k_permute<<<(N_EDGES + 255) / 256, 256, 0, stream>>>(src, dst, row_off, cursor,
                                                         perm_src, perm_dst);

    // ---- iterations ----
    for (int it = 0; it < N_ITERS; ++it) {
        hipMemsetAsync(r2agg, 0, (size_t)NPAD * 96 * 4, stream);
        k_edge_fused<<<512, 256, 0, stream>>>(hbf, perm_src, perm_dst,
                                              (const short8*)W1A, (const short8*)W2A,
                                              b1, b2, r2agg);
        k_node_mfma<<<(N_NODES + 63) / 64, 256, 0, stream>>>(inp, r2agg, row_off, h, hbf,
                                                     (const short8*)WbigA, (const short8*)WniA,
                                                     (const short8*)WnhA, (const short8*)WoutA,
                                                     vb3, bsum, b_hh, b_out, out, it);
    }
}

// Round 9
// 2115.785 us; speedup vs baseline: 1.5880x; 1.0576x over previous
//
#include <hip/hip_runtime.h>

#define N_NODES 50000
#define N_EDGES 800000
#define N_ITERS 7
#define NPAD 50048
#define NT16 (N_EDGES / 16)   // 50000 16-edge tiles

typedef __attribute__((ext_vector_type(8))) short short8;
typedef __attribute__((ext_vector_type(4))) float f32x4;

#define AROW 104   // wave-private relay row: 96 bf16 + 8 pad
#define XROW 296   // X row: 288 bf16 + 8 pad

static __device__ __forceinline__ unsigned short f2bf(float f) {
    unsigned int u = __float_as_uint(f);
    unsigned int r = (u + 0x7fffu + ((u >> 16) & 1u)) >> 16;
    return (unsigned short)r;
}
static __device__ __forceinline__ float bf2f(unsigned short u) {
    return __uint_as_float(((unsigned int)u) << 16);
}
static __device__ __forceinline__ float fast_tanh(float x) {
    float xc = fminf(fmaxf(x, -15.f), 15.f);
    float t = __expf(2.f * xc);
    return (t - 1.f) / (t + 1.f);
}

// one segmented-scan step over the 16-lane row group (row_shr:OFF, bound_ctrl=1)
template <int CTRL>
static __device__ __forceinline__ void seg_step(float (&s)[24], unsigned& fl) {
    unsigned fv = (unsigned)__builtin_amdgcn_update_dpp(0, (int)fl, CTRL, 0xf, 0xf, true);
    float g = fl ? 0.f : 1.f;
#pragma unroll
    for (int q = 0; q < 24; q++) {
        int sv = __builtin_amdgcn_update_dpp(0, __float_as_int(s[q]), CTRL, 0xf, 0xf, true);
        s[q] += __int_as_float(sv) * g;
    }
    fl |= fv;
}

// ---------------------------------------------------------------------------
// Wbig [256][288]: rows = r,z gates; cols = [W_ih[:, :64] | W_ih[:,64:]@W3 | W_hh]
__global__ __launch_bounds__(256) void k_build_wbig(const float* __restrict__ W_ih,
                                                    const float* __restrict__ W3,
                                                    const float* __restrict__ W_hh,
                                                    float* __restrict__ Wbig) {
    int idx = blockIdx.x * 256 + threadIdx.x;
    if (idx >= 256 * 288) return;
    int g = idx / 288, k = idx - g * 288;
    float v;
    if (k < 64) v = W_ih[g * 192 + k];
    else if (k < 160) {
        int kk = k - 64; float s = 0.f;
        for (int j = 0; j < 128; j++) s += W_ih[g * 192 + 64 + j] * W3[j * 96 + kk];
        v = s;
    } else v = W_hh[g * 128 + (k - 160)];
    Wbig[idx] = v;
}

// Wni [128][160]: n-gate input part (W_ih rows 256..383, with W3 fold)
__global__ __launch_bounds__(256) void k_build_wni(const float* __restrict__ W_ih,
                                                   const float* __restrict__ W3,
                                                   float* __restrict__ Wni) {
    int idx = blockIdx.x * 256 + threadIdx.x;
    if (idx >= 128 * 160) return;
    int g = idx / 160, k = idx - g * 160;
    int gg = 256 + g;
    float v;
    if (k < 64) v = W_ih[gg * 192 + k];
    else {
        int kk = k - 64; float s = 0.f;
        for (int j = 0; j < 128; j++) s += W_ih[gg * 192 + 64 + j] * W3[j * 96 + kk];
        v = s;
    }
    Wni[idx] = v;
}

__global__ __launch_bounds__(256) void k_vb3(const float* __restrict__ W_ih,
                                             const float* __restrict__ b3,
                                             float* __restrict__ vb3) {
    int g = blockIdx.x * 256 + threadIdx.x;
    if (g >= 384) return;
    float s = 0.f;
    for (int j = 0; j < 128; j++) s += W_ih[g * 192 + 64 + j] * b3[j];
    vb3[g] = s;
}

__global__ __launch_bounds__(256) void k_bsum(const float* __restrict__ b_ih,
                                              const float* __restrict__ b_hh,
                                              float* __restrict__ bsum) {
    int d = blockIdx.x * 256 + threadIdx.x;
    if (d >= 384) return;
    bsum[d] = b_ih[d] + (d < 256 ? b_hh[d] : 0.f);
}

// ---------------------------------------------------------------------------
// Pack: src fp32 (ld), element (row0+j, k) -> A-frags [Mt][KT][64][8]
__global__ __launch_bounds__(256) void k_pack2(const float* __restrict__ src,
                                               unsigned short* __restrict__ out,
                                               int Mt, int KT, int ld, int row0) {
    int idx = blockIdx.x * 256 + threadIdx.x;
    if (idx >= Mt * KT * 512) return;
    int jj = idx & 7;
    int l  = (idx >> 3) & 63;
    int tile = idx >> 9;
    int kt = tile % KT;
    int mt = tile / KT;
    int j = row0 + mt * 16 + (l & 15);
    int k = kt * 32 + (l >> 4) * 8 + jj;
    out[idx] = f2bf(src[(size_t)j * ld + k]);
}

// ---------------------------------------------------------------------------
// CSR build (once; ids fixed across iterations)
__global__ __launch_bounds__(256) void k_hist(const int* __restrict__ dst,
                                              int* __restrict__ counts) {
    int e = blockIdx.x * 256 + threadIdx.x;
    if (e < N_EDGES) atomicAdd(&counts[dst[e]], 1);
}

__global__ __launch_bounds__(1024) void k_scan(const int* __restrict__ counts,
                                               int* __restrict__ row_off) {
    __shared__ int sh[1024];
    int t = threadIdx.x;
    const int STR = 49;
    int base = t * STR;
    int s = 0;
    for (int i = 0; i < STR; i++) {
        int n = base + i;
        if (n < N_NODES) s += counts[n];
    }
    sh[t] = s;
    __syncthreads();
    for (int off = 1; off < 1024; off <<= 1) {
        int v = (t >= off) ? sh[t - off] : 0;
        __syncthreads();
        sh[t] += v;
        __syncthreads();
    }
    int run = (t == 0) ? 0 : sh[t - 1];
    for (int i = 0; i < STR; i++) {
        int n = base + i;
        if (n < N_NODES) { row_off[n] = run; run += counts[n]; }
    }
    if (t == 1023) row_off[N_NODES] = run;
}

__global__ __launch_bounds__(256) void k_permute(const int* __restrict__ src,
                                                 const int* __restrict__ dst,
                                                 const int* __restrict__ row_off,
                                                 int* __restrict__ cursor,
                                                 int* __restrict__ perm_src,
                                                 int* __restrict__ perm_dst) {
    int e = blockIdx.x * 256 + threadIdx.x;
    if (e >= N_EDGES) return;
    int d = dst[e];
    int pos = row_off[d] + atomicAdd(&cursor[d], 1);
    perm_src[pos] = src[e];
    perm_dst[pos] = d;
}

// ---------------------------------------------------------------------------
// Fused edge MLP + aggregation. Wave-independent 16-edge tiles, no barriers in
// the main loop. 3-stage pipeline: ids[t+2] in flight, gathers[t+1] in flight,
// process[t]. DPP segmented scan, atomics to node-major r2agg.
__global__ __launch_bounds__(256) void k_edge_fused(
    const unsigned short* __restrict__ hbf,   // [N][128] bf16
    const int* __restrict__ perm_src, const int* __restrict__ perm_dst,
    const short8* __restrict__ W1Ag,          // [6*8*64] frags
    const short8* __restrict__ W2Ag,          // [6*3*64] frags
    const float* __restrict__ b1,
    const float* __restrict__ b2,
    float* __restrict__ r2agg)                // [NPAD][96]
{
    __shared__ __attribute__((aligned(16))) short8 W1s[6 * 8 * 64];      // 49152 B
    __shared__ __attribute__((aligned(16))) short8 W2s[6 * 3 * 64];      // 18432 B
    __shared__ __attribute__((aligned(16))) unsigned short relay[4][16][AROW]; // 13312 B

    int t = threadIdx.x;
    int w = t >> 6, l = t & 63;
    int col = l & 15, krow = l >> 4;

    for (int i = t; i < 6 * 8 * 64; i += 256) W1s[i] = W1Ag[i];
    for (int i = t; i < 6 * 3 * 64; i += 256) W2s[i] = W2Ag[i];
    __syncthreads();   // only barrier in the kernel

    const int NW = 512 * 4;
    int wtid = blockIdx.x * 4 + w;

    auto mkmask = [&](int did) -> unsigned {
        int dp = __shfl_up(did, 1);
        return (unsigned)__ballot((col == 0) || (did != dp)) & 0xFFFFu;
    };
    auto gather = [&](int sid, int did, short8* fr) {
        const unsigned short* sr = hbf + (size_t)sid * 128 + krow * 8;
        const unsigned short* dr = hbf + (size_t)did * 128 + krow * 8;
#pragma unroll
        for (int kt = 0; kt < 4; kt++) fr[kt]     = *(const short8*)(sr + kt * 32);
#pragma unroll
        for (int kt = 0; kt < 4; kt++) fr[4 + kt] = *(const short8*)(dr + kt * 32);
    };

    auto process = [&](unsigned m16, int did, const short8* fr) {
        // ---- L1: c1 = W1 * m^T ----
        f32x4 c1[6] = {};
#pragma unroll
        for (int kt = 0; kt < 8; kt++) {
#pragma unroll
            for (int mt = 0; mt < 6; mt++)
                c1[mt] = __builtin_amdgcn_mfma_f32_16x16x32_bf16(W1s[(mt * 8 + kt) * 64 + l], fr[kt], c1[mt], 0, 0, 0);
        }
        // ---- a1 epilogue -> wave-private LDS relay ----
#pragma unroll
        for (int mt = 0; mt < 6; mt++) {
#pragma unroll
            for (int r = 0; r < 4; r += 2) {
                int j0 = mt * 16 + krow * 4 + r;
                float v0 = fmaxf(c1[mt][r]     + b1[j0],     0.f);
                float v1 = fmaxf(c1[mt][r + 1] + b1[j0 + 1], 0.f);
                unsigned int p = (unsigned int)f2bf(v0) | ((unsigned int)f2bf(v1) << 16);
                *(unsigned int*)(&relay[w][col][j0]) = p;
            }
        }
        // ---- L2 ----
        f32x4 c2[6] = {};
#pragma unroll
        for (int kt = 0; kt < 3; kt++) {
            short8 b = *(const short8*)(&relay[w][col][kt * 32 + krow * 8]);
#pragma unroll
            for (int mt = 0; mt < 6; mt++)
                c2[mt] = __builtin_amdgcn_mfma_f32_16x16x32_bf16(W2s[(mt * 3 + kt) * 64 + l], b, c2[mt], 0, 0, 0);
        }
        // ---- msg (bias+relu) stays in registers ----
        float s[24];
#pragma unroll
        for (int mt = 0; mt < 6; mt++)
#pragma unroll
            for (int r = 0; r < 4; r++) {
                int j = mt * 16 + krow * 4 + r;
                s[mt * 4 + r] = fmaxf(c2[mt][r] + b2[j], 0.f);
            }
        // ---- segmented inclusive scan over col (DPP row_shr within 16 lanes) ----
        unsigned fl = (m16 >> col) & 1u;
        seg_step<0x111>(s, fl);
        seg_step<0x112>(s, fl);
        seg_step<0x114>(s, fl);
        seg_step<0x118>(s, fl);
        // ---- segment-end lanes scatter ----
        bool is_end = (col == 15) || ((m16 >> (col + 1)) & 1u);
        if (is_end) {
            float* base = r2agg + (size_t)did * 96 + krow * 4;
#pragma unroll
            for (int mt = 0; mt < 6; mt++)
#pragma unroll
                for (int r = 0; r < 4; r++)
                    atomicAdd(base + mt * 16 + r, s[mt * 4 + r]);
        }
    };

    // ---- 3-stage pipelined tile loop ----
    int tA = wtid;                 // wtid < 2048 <= NT16 always
    unsigned mA, mB;
    int sidA = 0, didA = 0, sidB = 0, didB = 0, sidC = 0, didC = 0;
    short8 frA[8], frB[8];

    { int e = tA * 16 + col; sidA = perm_src[e]; didA = perm_dst[e]; }
    int tB = tA + NW;
    bool hasB = (tB < NT16);
    if (hasB) { int e = tB * 16 + col; sidB = perm_src[e]; didB = perm_dst[e]; }
    mA = mkmask(didA);
    gather(sidA, didA, frA);

    for (;;) {
        int tC = tB + NW;
        bool hasC = (tC < NT16);
        if (hasC) { int e = tC * 16 + col; sidC = perm_src[e]; didC = perm_dst[e]; }
        if (hasB) { mB = mkmask(didB); gather(sidB, didB, frB); }
        process(mA, didA, frA);
        if (!hasB) break;
        mA = mB; didA = didB;
#pragma unroll
        for (int i = 0; i < 8; i++) frA[i] = frB[i];
        sidB = sidC; didB = didC;
        tB = tC; hasB = hasC;
    }
}

// ---------------------------------------------------------------------------
// Node phase: 4 waves x 16 nodes, phased LDS weight staging (weights cross L2
// once per BLOCK, not once per wave). Gates GEMMs + GRU + out-proj + hbf.
__global__ __launch_bounds__(256) void k_node_mfma(
    const float* __restrict__ inp,      // [N][64]
    const float* __restrict__ r2agg,    // [NPAD][96]
    const int* __restrict__ row_off,    // [N+1]
    float* __restrict__ h,              // [N][128] fp32 in/out
    unsigned short* __restrict__ hbf,   // [N][128] bf16 in/out
    const short8* __restrict__ WbigA,   // 16x9 tiles
    const short8* __restrict__ WniA,    // 8x5
    const short8* __restrict__ WnhA,    // 8x4
    const short8* __restrict__ WoutA,   // 4x4
    const float* __restrict__ vb3,
    const float* __restrict__ bsum,
    const float* __restrict__ b_hh,
    const float* __restrict__ b_out,
    float* __restrict__ out, int iter)
{
    __shared__ __attribute__((aligned(16))) unsigned short X[4][16][XROW]; // 37888 B
    __shared__ __attribute__((aligned(16))) short8 Wstage[72 * 64];        // 73728 B
    int t = threadIdx.x;
    int w = t >> 6, l = t & 63;
    int nb = blockIdx.x * 64;
    int col = l & 15, krow = l >> 4;

    auto stageW = [&](const short8* src, int tiles, int dstoff) {
        int n = tiles * 64;
        for (int i = t; i < n; i += 256) Wstage[dstoff + i] = src[i];
    };

    // ---- stage X = [inp(64) | r2(96) | h(128)] bf16, and phase-1 weights ----
    for (int idx = t; idx < 64 * 32; idx += 256) {      // inp pairs
        int i = idx >> 5, kk = (idx & 31) << 1;
        int n = nb + i;
        float2 v = make_float2(0.f, 0.f);
        if (n < N_NODES) v = *(const float2*)(inp + (size_t)n * 64 + kk);
        unsigned int p = (unsigned int)f2bf(v.x) | ((unsigned int)f2bf(v.y) << 16);
        *(unsigned int*)(&X[i >> 4][i & 15][kk]) = p;
    }
    for (int idx = t; idx < 64 * 96; idx += 256) {      // r2 node-major
        int i = (int)((unsigned)idx / 96u), k = idx - i * 96;
        X[i >> 4][i & 15][64 + k] = f2bf(r2agg[(size_t)(nb + i) * 96 + k]);
    }
    for (int idx = t; idx < 64 * 16; idx += 256) {      // h: straight bf16 copy
        int i = idx >> 4, c = idx & 15;
        int n = nb + i;
        uint4 v = make_uint4(0, 0, 0, 0);
        if (n < N_NODES) v = ((const uint4*)(hbf + (size_t)n * 128))[c];
        *(uint4*)(&X[i >> 4][i & 15][160 + c * 8]) = v;
    }
    stageW(WbigA, 72, 0);                                // gates mt 0..7
    __syncthreads();

    // ---- gates r,z part 1: mt 0..7 ----
    f32x4 cg[16] = {};
#pragma unroll 3
    for (int kt = 0; kt < 9; kt++) {
        short8 b = *(const short8*)(&X[w][col][kt * 32 + krow * 8]);
#pragma unroll
        for (int mt = 0; mt < 8; mt++)
            cg[mt] = __builtin_amdgcn_mfma_f32_16x16x32_bf16(Wstage[(mt * 9 + kt) * 64 + l], b, cg[mt], 0, 0, 0);
    }
    __syncthreads();
    stageW(WbigA + 72 * 64, 72, 0);                      // gates mt 8..15
    __syncthreads();
#pragma unroll 3
    for (int kt = 0; kt < 9; kt++) {
        short8 b = *(const short8*)(&X[w][col][kt * 32 + krow * 8]);
#pragma unroll
        for (int mt = 0; mt < 8; mt++)
            cg[8 + mt] = __builtin_amdgcn_mfma_f32_16x16x32_bf16(Wstage[(mt * 9 + kt) * 64 + l], b, cg[8 + mt], 0, 0, 0);
    }
    __syncthreads();
    stageW(WniA, 40, 0);                                 // i_n
    stageW(WnhA, 32, 40 * 64);                           // h_n
    __syncthreads();

    // ---- i_n: [128 x 160] ----
    f32x4 ci[8] = {};
#pragma unroll
    for (int kt = 0; kt < 5; kt++) {
        short8 b = *(const short8*)(&X[w][col][kt * 32 + krow * 8]);
#pragma unroll
        for (int mt = 0; mt < 8; mt++)
            ci[mt] = __builtin_amdgcn_mfma_f32_16x16x32_bf16(Wstage[(mt * 5 + kt) * 64 + l], b, ci[mt], 0, 0, 0);
    }
    // ---- h_n: [128 x 128] ----
    f32x4 ch[8] = {};
#pragma unroll
    for (int kt = 0; kt < 4; kt++) {
        short8 b = *(const short8*)(&X[w][col][160 + kt * 32 + krow * 8]);
#pragma unroll
        for (int mt = 0; mt < 8; mt++)
            ch[mt] = __builtin_amdgcn_mfma_f32_16x16x32_bf16(Wstage[(40 * 64) + (mt * 4 + kt) * 64 + l], b, ch[mt], 0, 0, 0);
    }
    __syncthreads();
    stageW(WoutA, 16, 0);                                // out-proj weights (overlaps epilogue)

    int n = nb + w * 16 + col;
    bool valid = (n < N_NODES);
    float deg = 0.f;
    if (valid) deg = (float)(row_off[n + 1] - row_off[n]);

    // ---- GRU epilogue ----
#pragma unroll
    for (int mt = 0; mt < 8; mt++) {
        int d0 = mt * 16 + krow * 4;
        float4 ho = make_float4(0.f, 0.f, 0.f, 0.f);
        if (valid) ho = *(const float4*)(h + (size_t)n * 128 + d0);
        float hov[4] = {ho.x, ho.y, ho.z, ho.w};
        float hv[4];
#pragma unroll
        for (int r = 0; r < 4; r++) {
            int d = d0 + r;
            float rp = cg[mt][r]     + bsum[d]       + deg * vb3[d];
            float zp = cg[mt + 8][r] + bsum[128 + d] + deg * vb3[128 + d];
            float ip = ci[mt][r]     + bsum[256 + d] + deg * vb3[256 + d];
            float hp = ch[mt][r]     + b_hh[256 + d];
            float rg = 1.f / (1.f + __expf(-rp));
            float zg = 1.f / (1.f + __expf(-zp));
            float ng = fast_tanh(ip + rg * hp);
            hv[r] = (1.f - zg) * ng + zg * hov[r];
        }
        if (valid)
            *(float4*)(h + (size_t)n * 128 + d0) = make_float4(hv[0], hv[1], hv[2], hv[3]);
        unsigned int p0 = (unsigned int)f2bf(hv[0]) | ((unsigned int)f2bf(hv[1]) << 16);
        unsigned int p1 = (unsigned int)f2bf(hv[2]) | ((unsigned int)f2bf(hv[3]) << 16);
        *(unsigned int*)(&X[w][col][160 + d0])     = p0;
        *(unsigned int*)(&X[w][col][160 + d0 + 2]) = p1;
    }
    __syncthreads();   // h_new in X + WoutA staged

    // ---- out projection on h_new ----
    f32x4 co[4] = {};
#pragma unroll
    for (int kt = 0; kt < 4; kt++) {
        short8 b = *(const short8*)(&X[w][col][160 + kt * 32 + krow * 8]);
#pragma unroll
        for (int mt = 0; mt < 4; mt++)
            co[mt] = __builtin_amdgcn_mfma_f32_16x16x32_bf16(Wstage[(mt * 4 + kt) * 64 + l], b, co[mt], 0, 0, 0);
    }
    if (valid) {
        float* op = out + (size_t)iter * N_NODES * 64 + (size_t)n * 64;
#pragma unroll
        for (int mt = 0; mt < 4; mt++) {
            int o0 = mt * 16 + krow * 4;
            *(float4*)(op + o0) = make_float4(co[mt][0] + b_out[o0],     co[mt][1] + b_out[o0 + 1],
                                              co[mt][2] + b_out[o0 + 2], co[mt][3] + b_out[o0 + 3]);
        }
    }

    // ---- hbf writeback ----
    for (int idx = t; idx < 64 * 16; idx += 256) {
        int i = idx >> 4, c = idx & 15;
        int n2 = nb + i;
        if (n2 < N_NODES)
            ((uint4*)(hbf + (size_t)n2 * 128))[c] = *(const uint4*)(&X[i >> 4][i & 15][160 + c * 8]);
    }
}

// ---------------------------------------------------------------------------
extern "C" void kernel_launch(void* const* d_in, const int* in_sizes, int n_in,
                              void* d_out, int out_size, void* d_ws, size_t ws_size,
                              hipStream_t stream)
{
    const float* inp   = (const float*)d_in[0];
    const int*   src   = (const int*)d_in[1];
    const int*   dst   = (const int*)d_in[2];
    const float* W1    = (const float*)d_in[3];
    const float* b1    = (const float*)d_in[4];
    const float* W2    = (const float*)d_in[5];
    const float* b2    = (const float*)d_in[6];
    const float* W3    = (const float*)d_in[7];
    const float* b3    = (const float*)d_in[8];
    const float* W_ih  = (const float*)d_in[9];
    const float* W_hh  = (const float*)d_in[10];
    const float* b_ih  = (const float*)d_in[11];
    const float* b_hh  = (const float*)d_in[12];
    const float* W_out = (const float*)d_in[13];
    const float* b_out = (const float*)d_in[14];
    float* out = (float*)d_out;

    char* ws = (char*)d_ws;
    size_t off = 0;
    auto alloc = [&](size_t bytes) -> void* {
        void* p = ws + off;
        off += (bytes + 255) & ~(size_t)255;
        return p;
    };
    float* h       = (float*)alloc((size_t)N_NODES * 128 * 4);
    unsigned short* hbf = (unsigned short*)alloc((size_t)N_NODES * 128 * 2);
    float* r2agg   = (float*)alloc((size_t)NPAD * 96 * 4);
    float* Wbig    = (float*)alloc((size_t)256 * 288 * 4);
    float* Wni     = (float*)alloc((size_t)128 * 160 * 4);
    float* vb3     = (float*)alloc((size_t)384 * 4);
    float* bsum    = (float*)alloc((size_t)384 * 4);
    unsigned short* W1A   = (unsigned short*)alloc((size_t)6 * 8 * 512 * 2);
    unsigned short* W2A   = (unsigned short*)alloc((size_t)6 * 3 * 512 * 2);
    unsigned short* WbigA = (unsigned short*)alloc((size_t)16 * 9 * 512 * 2);
    unsigned short* WniA  = (unsigned short*)alloc((size_t)8 * 5 * 512 * 2);
    unsigned short* WnhA  = (unsigned short*)alloc((size_t)8 * 4 * 512 * 2);
    unsigned short* WoutA = (unsigned short*)alloc((size_t)4 * 4 * 512 * 2);
    int*   counts  = (int*)alloc((size_t)N_NODES * 4);
    int*   cursor  = (int*)alloc((size_t)N_NODES * 4);
    int*   row_off = (int*)alloc((size_t)(N_NODES + 1) * 4);
    int*   perm_src= (int*)alloc((size_t)N_EDGES * 4);
    int*   perm_dst= (int*)alloc((size_t)N_EDGES * 4);

    // ---- one-time preprocessing ----
    hipMemsetAsync(h, 0, (size_t)N_NODES * 128 * 4, stream);
    hipMemsetAsync(hbf, 0, (size_t)N_NODES * 128 * 2, stream);
    hipMemsetAsync(counts, 0, (size_t)N_NODES * 4, stream);
    hipMemsetAsync(cursor, 0, (size_t)N_NODES * 4, stream);

    k_build_wbig<<<(256 * 288 + 255) / 256, 256, 0, stream>>>(W_ih, W3, W_hh, Wbig);
    k_build_wni<<<(128 * 160 + 255) / 256, 256, 0, stream>>>(W_ih, W3, Wni);
    k_vb3<<<2, 256, 0, stream>>>(W_ih, b3, vb3);
    k_bsum<<<2, 256, 0, stream>>>(b_ih, b_hh, bsum);

    k_pack2<<<(6 * 8 * 512 + 255) / 256, 256, 0, stream>>>(W1, W1A, 6, 8, 256, 0);
    k_pack2<<<(6 * 3 * 512 + 255) / 256, 256, 0, stream>>>(W2, W2A, 6, 3, 96, 0);
    k_pack2<<<(16 * 9 * 512 + 255) / 256, 256, 0, stream>>>(Wbig, WbigA, 16, 9, 288, 0);
    k_pack2<<<(8 * 5 * 512 + 255) / 256, 256, 0, stream>>>(Wni, WniA, 8, 5, 160, 0);
    k_pack2<<<(8 * 4 * 512 + 255) / 256, 256, 0, stream>>>(W_hh, WnhA, 8, 4, 128, 256);
    k_pack2<<<(4 * 4 * 512 + 255) / 256, 256, 0, stream>>>(W_out, WoutA, 4, 4, 128, 0);

    k_hist<<<(N_EDGES + 255) / 256, 256, 0, stream>>>(dst, counts);
    k_scan<<<1, 1024, 0, stream>>>(counts, row_off);
    k_permute<<<(N_EDGES + 255) / 256, 256, 0, stream>>>(src, dst, row_off, cursor,
                                                         perm_src, perm_dst);

    // ---- iterations ----
    for (int it = 0; it < N_ITERS; ++it) {
        hipMemsetAsync(r2agg, 0, (size_t)NPAD * 96 * 4, stream);
        k_edge_fused<<<512, 256, 0, stream>>>(hbf, perm_src, perm_dst,
                                              (const short8*)W1A, (const short8*)W2A,
                                              b1, b2, r2agg);
        k_node_mfma<<<(N_NODES + 63) / 64, 256, 0, stream>>>(inp, r2agg, row_off, h, hbf,
                                                     (const short8*)WbigA, (const short8*)WniA,
                                                     (const short8*)WnhA, (const short8*)WoutA,
                                                     vb3, bsum, b_hh, b_out, out, it);
    }
}

// Round 11
// 1440.734 us; speedup vs baseline: 2.3321x; 1.4685x over previous
//
#include <hip/hip_runtime.h>

#define N_NODES 50000
#define N_EDGES 800000
#define N_ITERS 7
#define NPAD 50048
#define NT16 (N_EDGES / 16)   // 50000 16-edge tiles
#define TOTW 2048             // 512 blocks x 4 waves
#define TPW ((NT16 + TOTW - 1) / TOTW)   // 25 tiles per wave

typedef __attribute__((ext_vector_type(8))) short short8;
typedef __attribute__((ext_vector_type(4))) float f32x4;

#define AROW 104   // wave-private relay row: 96 bf16 + 8 pad
#define XROW 296   // X row: 288 bf16 + 8 pad

static __device__ __forceinline__ unsigned short f2bf(float f) {
    unsigned int u = __float_as_uint(f);
    unsigned int r = (u + 0x7fffu + ((u >> 16) & 1u)) >> 16;
    return (unsigned short)r;
}
static __device__ __forceinline__ float bf2f(unsigned short u) {
    return __uint_as_float(((unsigned int)u) << 16);
}
static __device__ __forceinline__ float fast_tanh(float x) {
    float xc = fminf(fmaxf(x, -15.f), 15.f);
    float t = __expf(2.f * xc);
    return (t - 1.f) / (t + 1.f);
}
// row_ror:1 (0x121): lane i <- lane (i-1) mod 16, so col0 receives col15.
// (NOT 0x12F/row_ror:15 — shr:N means lane i <- lane i-N, so ror:1 wraps 15->0.)
static __device__ __forceinline__ float ror_prev(float x) {
    return __int_as_float(__builtin_amdgcn_update_dpp(0, __float_as_int(x), 0x121, 0xf, 0xf, true));
}

// one segmented-scan step over the 16-lane row group (row_shr:CTRL&15, bound_ctrl=1)
template <int CTRL>
static __device__ __forceinline__ void seg_step(float (&s)[24], unsigned& fl) {
    unsigned fv = (unsigned)__builtin_amdgcn_update_dpp(0, (int)fl, CTRL, 0xf, 0xf, true);
    float g = fl ? 0.f : 1.f;
#pragma unroll
    for (int q = 0; q < 24; q++) {
        int sv = __builtin_amdgcn_update_dpp(0, __float_as_int(s[q]), CTRL, 0xf, 0xf, true);
        s[q] += __int_as_float(sv) * g;
    }
    fl |= fv;
}

// ---------------------------------------------------------------------------
// Wbig [256][288]: rows = r,z gates; cols = [W_ih[:, :64] | W_ih[:,64:]@W3 | W_hh]
__global__ __launch_bounds__(256) void k_build_wbig(const float* __restrict__ W_ih,
                                                    const float* __restrict__ W3,
                                                    const float* __restrict__ W_hh,
                                                    float* __restrict__ Wbig) {
    int idx = blockIdx.x * 256 + threadIdx.x;
    if (idx >= 256 * 288) return;
    int g = idx / 288, k = idx - g * 288;
    float v;
    if (k < 64) v = W_ih[g * 192 + k];
    else if (k < 160) {
        int kk = k - 64; float s = 0.f;
        for (int j = 0; j < 128; j++) s += W_ih[g * 192 + 64 + j] * W3[j * 96 + kk];
        v = s;
    } else v = W_hh[g * 128 + (k - 160)];
    Wbig[idx] = v;
}

// Wni [128][160]: n-gate input part (W_ih rows 256..383, with W3 fold)
__global__ __launch_bounds__(256) void k_build_wni(const float* __restrict__ W_ih,
                                                   const float* __restrict__ W3,
                                                   float* __restrict__ Wni) {
    int idx = blockIdx.x * 256 + threadIdx.x;
    if (idx >= 128 * 160) return;
    int g = idx / 160, k = idx - g * 160;
    int gg = 256 + g;
    float v;
    if (k < 64) v = W_ih[gg * 192 + k];
    else {
        int kk = k - 64; float s = 0.f;
        for (int j = 0; j < 128; j++) s += W_ih[gg * 192 + 64 + j] * W3[j * 96 + kk];
        v = s;
    }
    Wni[idx] = v;
}

__global__ __launch_bounds__(256) void k_vb3(const float* __restrict__ W_ih,
                                             const float* __restrict__ b3,
                                             float* __restrict__ vb3) {
    int g = blockIdx.x * 256 + threadIdx.x;
    if (g >= 384) return;
    float s = 0.f;
    for (int j = 0; j < 128; j++) s += W_ih[g * 192 + 64 + j] * b3[j];
    vb3[g] = s;
}

__global__ __launch_bounds__(256) void k_bsum(const float* __restrict__ b_ih,
                                              const float* __restrict__ b_hh,
                                              float* __restrict__ bsum) {
    int d = blockIdx.x * 256 + threadIdx.x;
    if (d >= 384) return;
    bsum[d] = b_ih[d] + (d < 256 ? b_hh[d] : 0.f);
}

// ---------------------------------------------------------------------------
// Pack: src fp32 (ld), element (row0+j, k) -> A-frags [Mt][KT][64][8]
__global__ __launch_bounds__(256) void k_pack2(const float* __restrict__ src,
                                               unsigned short* __restrict__ out,
                                               int Mt, int KT, int ld, int row0) {
    int idx = blockIdx.x * 256 + threadIdx.x;
    if (idx >= Mt * KT * 512) return;
    int jj = idx & 7;
    int l  = (idx >> 3) & 63;
    int tile = idx >> 9;
    int kt = tile % KT;
    int mt = tile / KT;
    int j = row0 + mt * 16 + (l & 15);
    int k = kt * 32 + (l >> 4) * 8 + jj;
    out[idx] = f2bf(src[(size_t)j * ld + k]);
}

// ---------------------------------------------------------------------------
// CSR build (once; ids fixed across iterations)
__global__ __launch_bounds__(256) void k_hist(const int* __restrict__ dst,
                                              int* __restrict__ counts) {
    int e = blockIdx.x * 256 + threadIdx.x;
    if (e < N_EDGES) atomicAdd(&counts[dst[e]], 1);
}

__global__ __launch_bounds__(1024) void k_scan(const int* __restrict__ counts,
                                               int* __restrict__ row_off) {
    __shared__ int sh[1024];
    int t = threadIdx.x;
    const int STR = 49;
    int base = t * STR;
    int s = 0;
    for (int i = 0; i < STR; i++) {
        int n = base + i;
        if (n < N_NODES) s += counts[n];
    }
    sh[t] = s;
    __syncthreads();
    for (int off = 1; off < 1024; off <<= 1) {
        int v = (t >= off) ? sh[t - off] : 0;
        __syncthreads();
        sh[t] += v;
        __syncthreads();
    }
    int run = (t == 0) ? 0 : sh[t - 1];
    for (int i = 0; i < STR; i++) {
        int n = base + i;
        if (n < N_NODES) { row_off[n] = run; run += counts[n]; }
    }
    if (t == 1023) row_off[N_NODES] = run;
}

__global__ __launch_bounds__(256) void k_permute(const int* __restrict__ src,
                                                 const int* __restrict__ dst,
                                                 const int* __restrict__ row_off,
                                                 int* __restrict__ cursor,
                                                 int* __restrict__ perm_src,
                                                 int* __restrict__ perm_dst) {
    int e = blockIdx.x * 256 + threadIdx.x;
    if (e >= N_EDGES) return;
    int d = dst[e];
    int pos = row_off[d] + atomicAdd(&cursor[d], 1);
    perm_src[pos] = src[e];
    perm_dst[pos] = d;
}

// ---------------------------------------------------------------------------
// Fused edge MLP + aggregation. Each wave owns TPW CONTIGUOUS 16-edge tiles.
// Register carry chain across tiles: a node spanning tiles accumulates in
// registers; each node emitted ONCE via plain float4 stores. Atomics only at
// wave-range boundaries. DPP segmented scan; 3-stage load pipeline.
__global__ __launch_bounds__(256) void k_edge_fused(
    const unsigned short* __restrict__ hbf,   // [N][128] bf16
    const int* __restrict__ perm_src, const int* __restrict__ perm_dst,
    const short8* __restrict__ W1Ag,          // [6*8*64] frags
    const short8* __restrict__ W2Ag,          // [6*3*64] frags
    const float* __restrict__ b1,
    const float* __restrict__ b2,
    float* __restrict__ r2agg)                // [NPAD][96]
{
    __shared__ __attribute__((aligned(16))) short8 W1s[6 * 8 * 64];      // 49152 B
    __shared__ __attribute__((aligned(16))) short8 W2s[6 * 3 * 64];      // 18432 B
    __shared__ __attribute__((aligned(16))) unsigned short relay[4][16][AROW]; // 13312 B

    int t = threadIdx.x;
    int w = t >> 6, l = t & 63;
    int col = l & 15, krow = l >> 4;

    for (int i = t; i < 6 * 8 * 64; i += 256) W1s[i] = W1Ag[i];
    for (int i = t; i < 6 * 3 * 64; i += 256) W2s[i] = W2Ag[i];
    __syncthreads();   // only barrier in the kernel

    int wtid = blockIdx.x * 4 + w;
    int tlo = wtid * TPW;
    int thi = tlo + TPW; if (thi > NT16) thi = NT16;
    if (tlo >= thi) return;

    auto mkmask = [&](int did) -> unsigned {
        int dp = __shfl_up(did, 1);
        return (unsigned)__ballot((col == 0) || (did != dp)) & 0xFFFFu;
    };
    auto gather = [&](int sid, int did, short8* fr) {
        const unsigned short* sr = hbf + (size_t)sid * 128 + krow * 8;
        const unsigned short* dr = hbf + (size_t)did * 128 + krow * 8;
#pragma unroll
        for (int kt = 0; kt < 4; kt++) fr[kt]     = *(const short8*)(sr + kt * 32);
#pragma unroll
        for (int kt = 0; kt < 4; kt++) fr[4 + kt] = *(const short8*)(dr + kt * 32);
    };

    float carry[24];
#pragma unroll
    for (int q = 0; q < 24; q++) carry[q] = 0.f;
    bool head = true;   // carry chain touches the wave's first edge

    auto process = [&](unsigned m16, int did, const short8* fr,
                       bool continuing, bool lastTile) {
        // ---- L1: c1 = W1 * m^T ----
        f32x4 c1[6] = {};
#pragma unroll
        for (int kt = 0; kt < 8; kt++) {
#pragma unroll
            for (int mt = 0; mt < 6; mt++)
                c1[mt] = __builtin_amdgcn_mfma_f32_16x16x32_bf16(W1s[(mt * 8 + kt) * 64 + l], fr[kt], c1[mt], 0, 0, 0);
        }
        // ---- a1 epilogue -> wave-private LDS relay ----
#pragma unroll
        for (int mt = 0; mt < 6; mt++) {
#pragma unroll
            for (int r = 0; r < 4; r += 2) {
                int j0 = mt * 16 + krow * 4 + r;
                float v0 = fmaxf(c1[mt][r]     + b1[j0],     0.f);
                float v1 = fmaxf(c1[mt][r + 1] + b1[j0 + 1], 0.f);
                unsigned int p = (unsigned int)f2bf(v0) | ((unsigned int)f2bf(v1) << 16);
                *(unsigned int*)(&relay[w][col][j0]) = p;
            }
        }
        // ---- L2 ----
        f32x4 c2[6] = {};
#pragma unroll
        for (int kt = 0; kt < 3; kt++) {
            short8 b = *(const short8*)(&relay[w][col][kt * 32 + krow * 8]);
#pragma unroll
            for (int mt = 0; mt < 6; mt++)
                c2[mt] = __builtin_amdgcn_mfma_f32_16x16x32_bf16(W2s[(mt * 3 + kt) * 64 + l], b, c2[mt], 0, 0, 0);
        }
        // ---- msg (bias+relu) in registers; inject carry at col0 ----
        float s[24];
#pragma unroll
        for (int mt = 0; mt < 6; mt++)
#pragma unroll
            for (int r = 0; r < 4; r++) {
                int j = mt * 16 + krow * 4 + r;
                float v = fmaxf(c2[mt][r] + b2[j], 0.f);
                s[mt * 4 + r] = v + ((col == 0) ? carry[mt * 4 + r] : 0.f);
            }
        // ---- segmented inclusive scan over col ----
        unsigned fl = (m16 >> col) & 1u;
        seg_step<0x111>(s, fl);
        seg_step<0x112>(s, fl);
        seg_step<0x114>(s, fl);
        seg_step<0x118>(s, fl);
        // ---- emission ----
        bool is_end = (col == 15) || ((m16 >> (col + 1)) & 1u);
        if (is_end && !((col == 15) && continuing)) {
            unsigned lowmask = (2u << col) - 1u;
            bool first_seg = (__popc(m16 & lowmask) == 1);
            bool use_atomic = (first_seg && head) || ((col == 15) && lastTile);
            float* base = r2agg + (size_t)did * 96 + krow * 4;
            if (use_atomic) {
#pragma unroll
                for (int mt = 0; mt < 6; mt++)
#pragma unroll
                    for (int r = 0; r < 4; r++)
                        atomicAdd(base + mt * 16 + r, s[mt * 4 + r]);
            } else {
#pragma unroll
                for (int mt = 0; mt < 6; mt++)
                    *(float4*)(base + mt * 16) = make_float4(s[mt * 4], s[mt * 4 + 1],
                                                             s[mt * 4 + 2], s[mt * 4 + 3]);
            }
        }
        // ---- carry update (wave-uniform) ----
        if (continuing) {
            head = head && (m16 == 1u);
#pragma unroll
            for (int q = 0; q < 24; q++) carry[q] = ror_prev(s[q]);
        } else {
            head = false;
#pragma unroll
            for (int q = 0; q < 24; q++) carry[q] = 0.f;
        }
    };

    // ---- 3-stage pipelined contiguous-tile loop ----
    int tA = tlo;
    unsigned mA, mB;
    int sidA = 0, didA = 0, sidB = 0, didB = 0, sidC = 0, didC = 0;
    short8 frA[8], frB[8];

    { int e = tA * 16 + col; sidA = perm_src[e]; didA = perm_dst[e]; }
    bool hasB = (tA + 1 < thi);
    if (hasB) { int e = (tA + 1) * 16 + col; sidB = perm_src[e]; didB = perm_dst[e]; }
    mA = mkmask(didA);
    gather(sidA, didA, frA);

    for (;;) {
        bool hasC = (tA + 2 < thi);
        if (hasC) { int e = (tA + 2) * 16 + col; sidC = perm_src[e]; didC = perm_dst[e]; }
        if (hasB) { mB = mkmask(didB); gather(sidB, didB, frB); }
        bool continuing = hasB && (__shfl(didA, 15) == __shfl(didB, 0));
        process(mA, didA, frA, continuing, !hasB);
        if (!hasB) break;
        mA = mB; didA = didB;
#pragma unroll
        for (int i = 0; i < 8; i++) frA[i] = frB[i];
        sidB = sidC; didB = didC;
        hasB = hasC;
        tA++;
    }
}

// ---------------------------------------------------------------------------
// Node phase: 4 waves x 64 shared nodes; wave w owns d-range [32w,32w+32)
// of all gates (and out rows [16w,16w+16)). Weights read once per wave with
// x4 B-frag reuse. 3 barriers, no weight staging.
__global__ __launch_bounds__(256) void k_node_mfma(
    const float* __restrict__ inp,      // [N][64]
    const float* __restrict__ r2agg,    // [NPAD][96]
    const int* __restrict__ row_off,    // [N+1]
    float* __restrict__ h,              // [N][128] fp32 in/out
    unsigned short* __restrict__ hbf,   // [N][128] bf16 in/out
    const short8* __restrict__ WbigA,   // [16][9] tiles
    const short8* __restrict__ WniA,    // [8][5]
    const short8* __restrict__ WnhA,    // [8][4]
    const short8* __restrict__ WoutA,   // [4][4]
    const float* __restrict__ vb3,
    const float* __restrict__ bsum,
    const float* __restrict__ b_hh,
    const float* __restrict__ b_out,
    float* __restrict__ out, int iter)
{
    __shared__ __attribute__((aligned(16))) unsigned short X[4][16][XROW]; // 37888 B
    __shared__ float degs[64];
    int t = threadIdx.x;
    int w = t >> 6, l = t & 63;
    int nb = blockIdx.x * 64;
    int col = l & 15, krow = l >> 4;

    // ---- stage X = [inp(64) | r2(96) | h(128)] bf16 + degs ----
    for (int idx = t; idx < 64 * 32; idx += 256) {
        int i = idx >> 5, kk = (idx & 31) << 1;
        int n = nb + i;
        float2 v = make_float2(0.f, 0.f);
        if (n < N_NODES) v = *(const float2*)(inp + (size_t)n * 64 + kk);
        unsigned int p = (unsigned int)f2bf(v.x) | ((unsigned int)f2bf(v.y) << 16);
        *(unsigned int*)(&X[i >> 4][i & 15][kk]) = p;
    }
    for (int idx = t; idx < 64 * 96; idx += 256) {
        int i = (int)((unsigned)idx / 96u), k = idx - i * 96;
        X[i >> 4][i & 15][64 + k] = f2bf(r2agg[(size_t)(nb + i) * 96 + k]);
    }
    for (int idx = t; idx < 64 * 16; idx += 256) {
        int i = idx >> 4, c = idx & 15;
        int n = nb + i;
        uint4 v = make_uint4(0, 0, 0, 0);
        if (n < N_NODES) v = ((const uint4*)(hbf + (size_t)n * 128))[c];
        *(uint4*)(&X[i >> 4][i & 15][160 + c * 8]) = v;
    }
    if (t < 64) {
        int n = nb + t;
        degs[t] = (n < N_NODES) ? (float)(row_off[n + 1] - row_off[n]) : 0.f;
    }
    __syncthreads();

    // ---- GEMMs: wave w computes d in [32w, 32w+32) ----
    int mts[4] = {2 * w, 2 * w + 1, 8 + 2 * w, 9 + 2 * w};   // r lo/hi, z lo/hi
    f32x4 cg[4][4] = {};
#pragma unroll 3
    for (int kt = 0; kt < 9; kt++) {
        short8 b[4];
#pragma unroll
        for (int bf = 0; bf < 4; bf++) b[bf] = *(const short8*)(&X[bf][col][kt * 32 + krow * 8]);
#pragma unroll
        for (int mi = 0; mi < 4; mi++) {
            short8 a = WbigA[(mts[mi] * 9 + kt) * 64 + l];
#pragma unroll
            for (int bf = 0; bf < 4; bf++)
                cg[mi][bf] = __builtin_amdgcn_mfma_f32_16x16x32_bf16(a, b[bf], cg[mi][bf], 0, 0, 0);
        }
    }
    f32x4 ci[2][4] = {};
#pragma unroll
    for (int kt = 0; kt < 5; kt++) {
        short8 b[4];
#pragma unroll
        for (int bf = 0; bf < 4; bf++) b[bf] = *(const short8*)(&X[bf][col][kt * 32 + krow * 8]);
#pragma unroll
        for (int mi = 0; mi < 2; mi++) {
            short8 a = WniA[((2 * w + mi) * 5 + kt) * 64 + l];
#pragma unroll
            for (int bf = 0; bf < 4; bf++)
                ci[mi][bf] = __builtin_amdgcn_mfma_f32_16x16x32_bf16(a, b[bf], ci[mi][bf], 0, 0, 0);
        }
    }
    f32x4 ch[2][4] = {};
#pragma unroll
    for (int kt = 0; kt < 4; kt++) {
        short8 b[4];
#pragma unroll
        for (int bf = 0; bf < 4; bf++) b[bf] = *(const short8*)(&X[bf][col][160 + kt * 32 + krow * 8]);
#pragma unroll
        for (int mi = 0; mi < 2; mi++) {
            short8 a = WnhA[((2 * w + mi) * 4 + kt) * 64 + l];
#pragma unroll
            for (int bf = 0; bf < 4; bf++)
                ch[mi][bf] = __builtin_amdgcn_mfma_f32_16x16x32_bf16(a, b[bf], ch[mi][bf], 0, 0, 0);
        }
    }
    __syncthreads();   // all reads of old-h in X complete

    // ---- GRU epilogue: wave w writes d-range [32w,32w+32) for all 64 nodes ----
#pragma unroll
    for (int mi = 0; mi < 2; mi++) {
        int d0 = w * 32 + mi * 16 + krow * 4;
        float4 bsr = *(const float4*)(bsum + d0);
        float4 bsz = *(const float4*)(bsum + 128 + d0);
        float4 bsn = *(const float4*)(bsum + 256 + d0);
        float4 vbr = *(const float4*)(vb3 + d0);
        float4 vbz = *(const float4*)(vb3 + 128 + d0);
        float4 vbn = *(const float4*)(vb3 + 256 + d0);
        float4 bhn = *(const float4*)(b_hh + 256 + d0);
        float bsrv[4] = {bsr.x, bsr.y, bsr.z, bsr.w};
        float bszv[4] = {bsz.x, bsz.y, bsz.z, bsz.w};
        float bsnv[4] = {bsn.x, bsn.y, bsn.z, bsn.w};
        float vbrv[4] = {vbr.x, vbr.y, vbr.z, vbr.w};
        float vbzv[4] = {vbz.x, vbz.y, vbz.z, vbz.w};
        float vbnv[4] = {vbn.x, vbn.y, vbn.z, vbn.w};
        float bhnv[4] = {bhn.x, bhn.y, bhn.z, bhn.w};
#pragma unroll
        for (int bf = 0; bf < 4; bf++) {
            int n = nb + bf * 16 + col;
            bool valid = (n < N_NODES);
            float deg = degs[bf * 16 + col];
            float4 ho = make_float4(0.f, 0.f, 0.f, 0.f);
            if (valid) ho = *(const float4*)(h + (size_t)n * 128 + d0);
            float hov[4] = {ho.x, ho.y, ho.z, ho.w};
            float hv[4];
#pragma unroll
            for (int r = 0; r < 4; r++) {
                float rp = cg[mi][bf][r]     + bsrv[r] + deg * vbrv[r];
                float zp = cg[2 + mi][bf][r] + bszv[r] + deg * vbzv[r];
                float ip = ci[mi][bf][r]     + bsnv[r] + deg * vbnv[r];
                float hp = ch[mi][bf][r]     + bhnv[r];
                float rg = 1.f / (1.f + __expf(-rp));
                float zg = 1.f / (1.f + __expf(-zp));
                float ng = fast_tanh(ip + rg * hp);
                hv[r] = (1.f - zg) * ng + zg * hov[r];
            }
            if (valid)
                *(float4*)(h + (size_t)n * 128 + d0) = make_float4(hv[0], hv[1], hv[2], hv[3]);
            unsigned int p0 = (unsigned int)f2bf(hv[0]) | ((unsigned int)f2bf(hv[1]) << 16);
            unsigned int p1 = (unsigned int)f2bf(hv[2]) | ((unsigned int)f2bf(hv[3]) << 16);
            *(unsigned int*)(&X[bf][col][160 + d0])     = p0;
            *(unsigned int*)(&X[bf][col][160 + d0 + 2]) = p1;
        }
    }
    __syncthreads();   // h_new complete in X

    // ---- out projection: wave w computes rows [16w,16w+16) ----
    f32x4 co[4] = {};
#pragma unroll
    for (int kt = 0; kt < 4; kt++) {
        short8 a = WoutA[(w * 4 + kt) * 64 + l];
#pragma unroll
        for (int bf = 0; bf < 4; bf++) {
            short8 b = *(const short8*)(&X[bf][col][160 + kt * 32 + krow * 8]);
            co[bf] = __builtin_amdgcn_mfma_f32_16x16x32_bf16(a, b, co[bf], 0, 0, 0);
        }
    }
    {
        int o0 = w * 16 + krow * 4;
        float4 bo = *(const float4*)(b_out + o0);
#pragma unroll
        for (int bf = 0; bf < 4; bf++) {
            int n = nb + bf * 16 + col;
            if (n < N_NODES) {
                float* op = out + (size_t)iter * N_NODES * 64 + (size_t)n * 64 + o0;
                *(float4*)op = make_float4(co[bf][0] + bo.x, co[bf][1] + bo.y,
                                           co[bf][2] + bo.z, co[bf][3] + bo.w);
            }
        }
    }

    // ---- hbf writeback ----
    for (int idx = t; idx < 64 * 16; idx += 256) {
        int i = idx >> 4, c = idx & 15;
        int n2 = nb + i;
        if (n2 < N_NODES)
            ((uint4*)(hbf + (size_t)n2 * 128))[c] = *(const uint4*)(&X[i >> 4][i & 15][160 + c * 8]);
    }
}

// ---------------------------------------------------------------------------
extern "C" void kernel_launch(void* const* d_in, const int* in_sizes, int n_in,
                              void* d_out, int out_size, void* d_ws, size_t ws_size,
                              hipStream_t stream)
{
    const float* inp   = (const float*)d_in[0];
    const int*   src   = (const int*)d_in[1];
    const int*   dst   = (const int*)d_in[2];
    const float* W1    = (const float*)d_in[3];
    const float* b1    = (const float*)d_in[4];
    const float* W2    = (const float*)d_in[5];
    const float* b2    = (const float*)d_in[6];
    const float* W3    = (const float*)d_in[7];
    const float* b3    = (const float*)d_in[8];
    const float* W_ih  = (const float*)d_in[9];
    const float* W_hh  = (const float*)d_in[10];
    const float* b_ih  = (const float*)d_in[11];
    const float* b_hh  = (const float*)d_in[12];
    const float* W_out = (const float*)d_in[13];
    const float* b_out = (const float*)d_in[14];
    float* out = (float*)d_out;

    char* ws = (char*)d_ws;
    size_t off = 0;
    auto alloc = [&](size_t bytes) -> void* {
        void* p = ws + off;
        off += (bytes + 255) & ~(size_t)255;
        return p;
    };
    float* h       = (float*)alloc((size_t)N_NODES * 128 * 4);
    unsigned short* hbf = (unsigned short*)alloc((size_t)N_NODES * 128 * 2);
    float* r2agg   = (float*)alloc((size_t)NPAD * 96 * 4);
    float* Wbig    = (float*)alloc((size_t)256 * 288 * 4);
    float* Wni     = (float*)alloc((size_t)128 * 160 * 4);
    float* vb3     = (float*)alloc((size_t)384 * 4);
    float* bsum    = (float*)alloc((size_t)384 * 4);
    unsigned short* W1A   = (unsigned short*)alloc((size_t)6 * 8 * 512 * 2);
    unsigned short* W2A   = (unsigned short*)alloc((size_t)6 * 3 * 512 * 2);
    unsigned short* WbigA = (unsigned short*)alloc((size_t)16 * 9 * 512 * 2);
    unsigned short* WniA  = (unsigned short*)alloc((size_t)8 * 5 * 512 * 2);
    unsigned short* WnhA  = (unsigned short*)alloc((size_t)8 * 4 * 512 * 2);
    unsigned short* WoutA = (unsigned short*)alloc((size_t)4 * 4 * 512 * 2);
    int*   counts  = (int*)alloc((size_t)N_NODES * 4);
    int*   cursor  = (int*)alloc((size_t)N_NODES * 4);
    int*   row_off = (int*)alloc((size_t)(N_NODES + 1) * 4);
    int*   perm_src= (int*)alloc((size_t)N_EDGES * 4);
    int*   perm_dst= (int*)alloc((size_t)N_EDGES * 4);

    // ---- one-time preprocessing ----
    hipMemsetAsync(h, 0, (size_t)N_NODES * 128 * 4, stream);
    hipMemsetAsync(hbf, 0, (size_t)N_NODES * 128 * 2, stream);
    hipMemsetAsync(counts, 0, (size_t)N_NODES * 4, stream);
    hipMemsetAsync(cursor, 0, (size_t)N_NODES * 4, stream);

    k_build_wbig<<<(256 * 288 + 255) / 256, 256, 0, stream>>>(W_ih, W3, W_hh, Wbig);
    k_build_wni<<<(128 * 160 + 255) / 256, 256, 0, stream>>>(W_ih, W3, Wni);
    k_vb3<<<2, 256, 0, stream>>>(W_ih, b3, vb3);
    k_bsum<<<2, 256, 0, stream>>>(b_ih, b_hh, bsum);

    k_pack2<<<(6 * 8 * 512 + 255) / 256, 256, 0, stream>>>(W1, W1A, 6, 8, 256, 0);
    k_pack2<<<(6 * 3 * 512 + 255) / 256, 256, 0, stream>>>(W2, W2A, 6, 3, 96, 0);
    k_pack2<<<(16 * 9 * 512 + 255) / 256, 256, 0, stream>>>(Wbig, WbigA, 16, 9, 288, 0);
    k_pack2<<<(8 * 5 * 512 + 255) / 256, 256, 0, stream>>>(Wni, WniA, 8, 5, 160, 0);
    k_pack2<<<(8 * 4 * 512 + 255) / 256, 256, 0, stream>>>(W_hh, WnhA, 8, 4, 128, 256);
    k_pack2<<<(4 * 4 * 512 + 255) / 256, 256, 0, stream>>>(W_out, WoutA, 4, 4, 128, 0);

    k_hist<<<(N_EDGES + 255) / 256, 256, 0, stream>>>(dst, counts);
    k_scan<<<1, 1024, 0, stream>>>(counts, row_off);
    k_permute<<<(N_EDGES + 255) / 256, 256, 0, stream>>>(src, dst, row_off, cursor,
                                                         perm_src, perm_dst);

    // ---- iterations ----
    for (int it = 0; it < N_ITERS; ++it) {
        hipMemsetAsync(r2agg, 0, (size_t)NPAD * 96 * 4, stream);
        k_edge_fused<<<512, 256, 0, stream>>>(hbf, perm_src, perm_dst,
                                              (const short8*)W1A, (const short8*)W2A,
                                              b1, b2, r2agg);
        k_node_mfma<<<(N_NODES + 63) / 64, 256, 0, stream>>>(inp, r2agg, row_off, h, hbf,
                                                     (const short8*)WbigA, (const short8*)WniA,
                                                     (const short8*)WnhA, (const short8*)WoutA,
                                                     vb3, bsum, b_hh, b_out, out, it);
    }
}